// Round 11
// baseline (350.346 us; speedup 1.0000x reference)
//
#include <hip/hip_runtime.h>
#include <hip/hip_bf16.h>

#define D   256
#define NE  8
#define G   128
#define H0  256
#define H1  128
#define H2  64
#define TBR 128
#define NT  512
#define EPS 1e-5f

typedef unsigned short u16;
typedef __attribute__((ext_vector_type(8))) short bf16x8;
typedef __attribute__((ext_vector_type(4))) float f32x4;
typedef __attribute__((ext_vector_type(4))) unsigned short u16x4;

#define MFMA16(a,b,c) __builtin_amdgcn_mfma_f32_16x16x32_bf16((a),(b),(c),0,0,0)

// ws layout: tile-pairs of 1024 u16 (512 hi + 512 lo), wave-fragment order:
// lane l holds B[k = kt*32 + 8*(l>>4) + j][n = nt*16 + (l&15)], j=0..7.
// EXPERT tiles: hi = RNE-rounded bf16 (1-term consumption, lo unused).
// GATING tiles: hi = truncated, lo = remainder (2-term consumption).
#define TP_EW0 1024   // 8e * 16nt * 8kt
#define TP_EW1 512    // 8e * 8nt * 8kt
#define TP_EW2 128    // 8e * 4nt * 4kt
#define TP_GW1 64     // 8nt * 8kt
#define TP_GW2 4      // 1nt(padded 16 cols) * 4kt
#define TPO_EW1 (TP_EW0)
#define TPO_EW2 (TP_EW0 + TP_EW1)
#define TPO_GW1 (TP_EW0 + TP_EW1 + TP_EW2)
#define TPO_GW2 (TPO_GW1 + TP_GW1)
#define TP_TOTAL (TPO_GW2 + TP_GW2)
#define WS_BYTES ((size_t)TP_TOTAL * 2048)

__device__ __forceinline__ u16 rne_bf16(float v) {
  unsigned u = __float_as_uint(v);
  u += 0x7FFFu + ((u >> 16) & 1u);
  return (u16)(u >> 16);
}

// ---------------------------------------------------------------- repack ----
__global__ __launch_bounds__(256) void repack_w(
    const float* __restrict__ eW0, const float* __restrict__ eW1,
    const float* __restrict__ eW2, const float* __restrict__ gW1,
    const float* __restrict__ gW2, u16* __restrict__ ws)
{
  const int wid = (blockIdx.x * 256 + threadIdx.x) >> 6;
  const int l   = threadIdx.x & 63;
  if (wid >= TP_TOTAL) return;
  const float* src; int ncols, nt, kt; bool pad8 = false;
  const bool expert = (wid < TPO_GW1);   // expert tiles: 1-term RNE
  if (wid < TP_EW0) {
    int e = wid >> 7, r = wid & 127; nt = r >> 3; kt = r & 7;
    src = eW0 + (size_t)e * D * H0; ncols = H0;
  } else if (wid < TPO_EW2) {
    int w2 = wid - TPO_EW1; int e = w2 >> 6, r = w2 & 63; nt = r >> 3; kt = r & 7;
    src = eW1 + (size_t)e * H0 * H1; ncols = H1;
  } else if (wid < TPO_GW1) {
    int w3 = wid - TPO_EW2; int e = w3 >> 4, r = w3 & 15; nt = r >> 2; kt = r & 3;
    src = eW2 + (size_t)e * H1 * H2; ncols = H2;
  } else if (wid < TPO_GW2) {
    int w4 = wid - TPO_GW1; nt = w4 >> 3; kt = w4 & 7;
    src = gW1; ncols = G;
  } else {
    kt = wid - TPO_GW2; nt = 0;
    src = gW2; ncols = NE; pad8 = true;   // pad cols 8..15 with zeros
  }
  const int n  = nt * 16 + (l & 15);
  const int k0 = kt * 32 + 8 * (l >> 4);
  u16 hi[8], lo[8];
  #pragma unroll
  for (int j = 0; j < 8; ++j) {
    float v = (pad8 && (l & 15) >= 8) ? 0.f : src[(size_t)(k0 + j) * ncols + (pad8 ? (n & 7) : n)];
    if (expert) {
      hi[j] = rne_bf16(v);    // 1-term: round-to-nearest (truncation doubles err)
      lo[j] = 0;
    } else {
      unsigned u = __float_as_uint(v);
      hi[j] = (u16)(u >> 16);
      float hf = __uint_as_float(u & 0xFFFF0000u);
      lo[j] = (u16)(__float_as_uint(v - hf) >> 16);
    }
  }
  u16* dst = ws + (size_t)wid * 1024 + l * 8;
  *(u16x4*)(dst + 0)       = u16x4{hi[0], hi[1], hi[2], hi[3]};
  *(u16x4*)(dst + 4)       = u16x4{hi[4], hi[5], hi[6], hi[7]};
  *(u16x4*)(dst + 512 + 0) = u16x4{lo[0], lo[1], lo[2], lo[3]};
  *(u16x4*)(dst + 512 + 4) = u16x4{lo[4], lo[5], lo[6], lo[7]};
}

// ------------------------------------------------------------- main MFMA ----
struct Smem {
  u16 xnh[TBR * D];   // 64 KiB, persistent
  u16 h0h[TBR * H0];  // 64 KiB (gating hidden gh in cols 0..127 pre-experts)
  union {
    u16 h1h[TBR * H1];    // 32 KiB (experts)
    float ss[2][D];       // Phase A/B only
    float part[4][2][32]; // final reduction only
  } u;
};                        // total 163840 B = 160 KiB exactly -> 1 block/CU

__device__ __forceinline__ int swz512(int r, int c) {
  return (r * 512 + ((c * 2) ^ ((r & 7) << 4))) >> 1;   // u16 index, row stride 512B
}
__device__ __forceinline__ int swz256(int r, int c) {
  return (r * 256 + ((c * 2) ^ ((r & 7) << 4))) >> 1;   // u16 index, row stride 256B
}
__device__ __forceinline__ bf16x8 ldA(const u16* p, int idx) {
  return *(const bf16x8*)(p + idx);
}

// 1 block/CU is structural (160 KiB LDS). 2x4 wave grid (mq x nq) halves
// ds_read traffic vs R8 (bank conflicts 2.8e7 -> 1.1e7, measured R9), BUT
// per-loop live accumulators must stay <= 32 VGPRs (acc[4][2]) or the
// allocator spills at its 128 target (R9: acc[4][4]=64 -> 38 MB scratch).
// L0 therefore runs as two sequential ni-pair passes.
__global__ __launch_bounds__(NT, 2) void moe_mfma(
    const float* __restrict__ x,
    const float* __restrict__ in_g, const float* __restrict__ in_b,
    const float* __restrict__ in_m, const float* __restrict__ in_v,
    const float* __restrict__ gb1,
    const float* __restrict__ g_g, const float* __restrict__ g_b,
    const float* __restrict__ g_m, const float* __restrict__ g_v,
    const float* __restrict__ gb2,
    const float* __restrict__ eb0,
    const float* __restrict__ e0g, const float* __restrict__ e0b,
    const float* __restrict__ e0m, const float* __restrict__ e0v,
    const float* __restrict__ eb1,
    const float* __restrict__ e1g, const float* __restrict__ e1b,
    const float* __restrict__ e1m, const float* __restrict__ e1v,
    const float* __restrict__ eb2,
    const float* __restrict__ e2g, const float* __restrict__ e2b,
    const float* __restrict__ e2m, const float* __restrict__ e2v,
    const float* __restrict__ oW, const float* __restrict__ ob,
    const u16* __restrict__ ws, float* __restrict__ out)
{
  __shared__ Smem sm;
  const int t = threadIdx.x;
  const int l = t & 63;
  const int w = t >> 6;            // wave 0..7
  const int row0 = blockIdx.x * TBR;
  const int rA  = l & 15;
  const int kg8 = 8 * (l >> 4);
  const int lg4 = (l >> 4) * 4;
  const int mq  = w >> 2;          // m-quadrant: m-tiles mq*4 .. mq*4+3
  const int nq  = w & 3;           // n-quadrant
  const int wg  = w >> 1;          // L2 / gating m-group (m-tiles 2wg, 2wg+1)
  const int np  = w & 1;           // L2 n-pair

  // ---- Phase A: input-BN scale/shift -> LDS (u region, dead until experts)
  if (t < D) {
    float s = in_g[t] * rsqrtf(in_v[t] + EPS);
    sm.u.ss[0][t] = s;
    sm.u.ss[1][t] = in_b[t] - in_m[t] * s;
  }
  __syncthreads();

  // ---- Phase B: load x, BN, RNE bf16 -> xnh (swizzled); 2 passes of 64 rows
  #pragma unroll
  for (int pass = 0; pass < 2; ++pass) {
    const int row = (t >> 3) + pass * 64;
    #pragma unroll
    for (int j = 0; j < 8; ++j) {
      const int cb = ((t & 7) + j * 8) * 4;
      const float4 xv = *(const float4*)(x + (size_t)(row0 + row) * D + cb);
      u16 h4[4];
      #pragma unroll
      for (int q = 0; q < 4; ++q) {
        float val = fmaf(((const float*)&xv)[q], sm.u.ss[0][cb + q], sm.u.ss[1][cb + q]);
        h4[q] = rne_bf16(val);
      }
      *(u16x4*)(sm.xnh + swz512(row, cb)) = u16x4{h4[0], h4[1], h4[2], h4[3]};
    }
  }
  __syncthreads();

  // ---- Phase C: gating hidden gh = relu(bn(xn@gW1+gb1)) -> h0h cols 0..127
  // wave (mq,nq): m-tiles mq*4..+3, n-tiles nq*2..+1 (2-term exact gW1)
  {
    f32x4 acc[4][2] = {};
    #pragma unroll
    for (int kt = 0; kt < 8; ++kt) {
      bf16x8 ah[4];
      #pragma unroll
      for (int mi = 0; mi < 4; ++mi)
        ah[mi] = ldA(sm.xnh, swz512((mq * 4 + mi) * 16 + rA, kt * 32 + kg8));
      #pragma unroll
      for (int ni = 0; ni < 2; ++ni) {
        const size_t tp = (size_t)TPO_GW1 + (size_t)(nq * 2 + ni) * 8 + kt;
        const bf16x8 wh = *((const bf16x8*)(ws + tp * 1024) + l);
        const bf16x8 wl = *((const bf16x8*)(ws + tp * 1024 + 512) + l);
        #pragma unroll
        for (int mi = 0; mi < 4; ++mi) {
          acc[mi][ni] = MFMA16(ah[mi], wh, acc[mi][ni]);
          acc[mi][ni] = MFMA16(ah[mi], wl, acc[mi][ni]);
        }
      }
    }
    #pragma unroll
    for (int ni = 0; ni < 2; ++ni) {
      const int c = (nq * 2 + ni) * 16 + rA;
      const float s  = g_g[c] * rsqrtf(g_v[c] + EPS);
      const float sh = fmaf(gb1[c] - g_m[c], s, g_b[c]);
      #pragma unroll
      for (int mi = 0; mi < 4; ++mi)
        #pragma unroll
        for (int r = 0; r < 4; ++r)
          sm.h0h[swz512((mq * 4 + mi) * 16 + lg4 + r, c)] =
              rne_bf16(fmaxf(fmaf(acc[mi][ni][r], s, sh), 0.f));
    }
  }
  __syncthreads();

  // ---- Phase D: gate logits via MFMA (padded gW2), in-register softmax
  // wave computes gates for m-tiles {2wg, 2wg+1} (matches its L2 rows)
  f32x4 gmine[2];  // gate[row=(2wg+mi)*16+lg4+r][expert=rA], rA<8 valid
  #pragma unroll
  for (int mi = 0; mi < 2; ++mi) {
    f32x4 acc = {};
    #pragma unroll
    for (int kt = 0; kt < 4; ++kt) {
      const bf16x8 ah = ldA(sm.h0h, swz512((2 * wg + mi) * 16 + rA, kt * 32 + kg8));
      const size_t tp = (size_t)TPO_GW2 + kt;
      const bf16x8 wh = *((const bf16x8*)(ws + tp * 1024) + l);
      const bf16x8 wl = *((const bf16x8*)(ws + tp * 1024 + 512) + l);
      acc = MFMA16(ah, wh, acc);
      acc = MFMA16(ah, wl, acc);
    }
    #pragma unroll
    for (int r = 0; r < 4; ++r) {
      float v = (rA < 8) ? (acc[r] + gb2[rA]) : -3.4e38f;
      float mx = v;
      mx = fmaxf(mx, __shfl_xor(mx, 1));
      mx = fmaxf(mx, __shfl_xor(mx, 2));
      mx = fmaxf(mx, __shfl_xor(mx, 4));
      mx = fmaxf(mx, __shfl_xor(mx, 8));
      float p = expf(v - mx);          // -inf lanes -> 0
      float ssum = p;
      ssum += __shfl_xor(ssum, 1);
      ssum += __shfl_xor(ssum, 2);
      ssum += __shfl_xor(ssum, 4);
      ssum += __shfl_xor(ssum, 8);
      gmine[mi][r] = p / ssum;
    }
  }
  __syncthreads();

  // ---- Phase E: experts (2 barriers per expert); 1-term RNE weights
  f32x4 comb[2][2] = {};   // [mi][nti]
  for (int e = 0; e < NE; ++e) {
    // L0: h0 = relu(bn(xn @ eW0[e] + eb0));
    // wave (mq,nq): m-tiles mq*4..+3, n-tiles nq*4..+3 — run as TWO
    // sequential ni-pair passes so live acc stays at acc[4][2]=32 VGPRs.
    #pragma unroll
    for (int half = 0; half < 2; ++half) {
      f32x4 acc[4][2] = {};
      #pragma unroll
      for (int kt = 0; kt < 8; ++kt) {
        bf16x8 ah[4];
        #pragma unroll
        for (int mi = 0; mi < 4; ++mi)
          ah[mi] = ldA(sm.xnh, swz512((mq * 4 + mi) * 16 + rA, kt * 32 + kg8));
        #pragma unroll
        for (int ni = 0; ni < 2; ++ni) {
          const size_t tp = ((size_t)e * 16 + nq * 4 + half * 2 + ni) * 8 + kt;
          const bf16x8 wh = *((const bf16x8*)(ws + tp * 1024) + l);
          #pragma unroll
          for (int mi = 0; mi < 4; ++mi)
            acc[mi][ni] = MFMA16(ah[mi], wh, acc[mi][ni]);
        }
      }
      #pragma unroll
      for (int ni = 0; ni < 2; ++ni) {
        const int c = (nq * 4 + half * 2 + ni) * 16 + rA;
        const float s  = e0g[e * H0 + c] * rsqrtf(e0v[e * H0 + c] + EPS);
        const float sh = fmaf(eb0[e * H0 + c] - e0m[e * H0 + c], s, e0b[e * H0 + c]);
        #pragma unroll
        for (int mi = 0; mi < 4; ++mi)
          #pragma unroll
          for (int r = 0; r < 4; ++r)
            sm.h0h[swz512((mq * 4 + mi) * 16 + lg4 + r, c)] =
                rne_bf16(fmaxf(fmaf(acc[mi][ni][r], s, sh), 0.f));
      }
    }
    __syncthreads();
    // L1: h1 = relu(bn(h0 @ eW1[e] + eb1));
    // wave (mq,nq): m-tiles mq*4..+3, n-tiles nq*2..+1 (acc[4][2]=32 VGPRs)
    {
      f32x4 acc[4][2] = {};
      #pragma unroll
      for (int kt = 0; kt < 8; ++kt) {
        bf16x8 ah[4];
        #pragma unroll
        for (int mi = 0; mi < 4; ++mi)
          ah[mi] = ldA(sm.h0h, swz512((mq * 4 + mi) * 16 + rA, kt * 32 + kg8));
        #pragma unroll
        for (int ni = 0; ni < 2; ++ni) {
          const size_t tp = TPO_EW1 + ((size_t)e * 8 + nq * 2 + ni) * 8 + kt;
          const bf16x8 wh = *((const bf16x8*)(ws + tp * 1024) + l);
          #pragma unroll
          for (int mi = 0; mi < 4; ++mi)
            acc[mi][ni] = MFMA16(ah[mi], wh, acc[mi][ni]);
        }
      }
      #pragma unroll
      for (int ni = 0; ni < 2; ++ni) {
        const int c = (nq * 2 + ni) * 16 + rA;
        const float s  = e1g[e * H1 + c] * rsqrtf(e1v[e * H1 + c] + EPS);
        const float sh = fmaf(eb1[e * H1 + c] - e1m[e * H1 + c], s, e1b[e * H1 + c]);
        #pragma unroll
        for (int mi = 0; mi < 4; ++mi)
          #pragma unroll
          for (int r = 0; r < 4; ++r)
            sm.u.h1h[swz256((mq * 4 + mi) * 16 + lg4 + r, c)] =
                rne_bf16(fmaxf(fmaf(acc[mi][ni][r], s, sh), 0.f));
      }
    }
    __syncthreads();
    // L2 + gated combine (h2 stays in registers);
    // wave -> m-tiles {2wg, 2wg+1}, n-tiles {2np, 2np+1}
    #pragma unroll
    for (int nti = 0; nti < 2; ++nti) {
      f32x4 acc2[2] = {};
      #pragma unroll
      for (int kt = 0; kt < 4; ++kt) {
        const size_t tp = TPO_EW2 + ((size_t)e * 4 + 2 * np + nti) * 4 + kt;
        const bf16x8 wh = *((const bf16x8*)(ws + tp * 1024) + l);
        #pragma unroll
        for (int mi = 0; mi < 2; ++mi) {
          const bf16x8 ah = ldA(sm.u.h1h, swz256((2 * wg + mi) * 16 + rA, kt * 32 + kg8));
          acc2[mi] = MFMA16(ah, wh, acc2[mi]);
        }
      }
      const int c = (2 * np + nti) * 16 + rA;
      const float s  = e2g[e * H2 + c] * rsqrtf(e2v[e * H2 + c] + EPS);
      const float sh = fmaf(eb2[e * H2 + c] - e2m[e * H2 + c], s, e2b[e * H2 + c]);
      #pragma unroll
      for (int mi = 0; mi < 2; ++mi)
        #pragma unroll
        for (int r = 0; r < 4; ++r) {
          const float gt = __shfl(gmine[mi][r], (l & 48) | e);  // gate[row][e]
          comb[mi][nti][r] = fmaf(gt, fmaxf(fmaf(acc2[mi][r], s, sh), 0.f),
                                  comb[mi][nti][r]);
        }
    }
    // hazard-free: h0h rewritten only after post-L1 barrier of this expert;
    // h1h rewritten only after post-L0 barrier of next expert.
  }

  // ---- Phase F: out = comb @ oW + ob (part aliases h1h -> barrier first)
  const float w0 = oW[(2 * np + 0) * 16 + rA];
  const float w1 = oW[(2 * np + 1) * 16 + rA];
  __syncthreads();
  #pragma unroll
  for (int mi = 0; mi < 2; ++mi)
    #pragma unroll
    for (int r = 0; r < 4; ++r) {
      float sx = comb[mi][0][r] * w0 + comb[mi][1][r] * w1;
      sx += __shfl_xor(sx, 1);
      sx += __shfl_xor(sx, 2);
      sx += __shfl_xor(sx, 4);
      sx += __shfl_xor(sx, 8);
      if (rA == 0) sm.u.part[wg][np][mi * 16 + lg4 + r] = sx;
    }
  __syncthreads();
  if (t < TBR)
    out[row0 + t] = sm.u.part[t >> 5][0][t & 31] +
                    sm.u.part[t >> 5][1][t & 31] + ob[0];
}

// ------------------------------------------------- fp32 fallback (verified) -
struct SmemF {
  float xn[16][D]; float h0[16][H0]; float h1[16][H1]; float gates[16][NE];
};
__global__ __launch_bounds__(256, 2) void moe_fused_fp32(
    const float* __restrict__ x,
    const float* __restrict__ in_g, const float* __restrict__ in_b,
    const float* __restrict__ in_m, const float* __restrict__ in_v,
    const float* __restrict__ gW1, const float* __restrict__ gb1,
    const float* __restrict__ g_g, const float* __restrict__ g_b,
    const float* __restrict__ g_m, const float* __restrict__ g_v,
    const float* __restrict__ gW2, const float* __restrict__ gb2,
    const float* __restrict__ eW0, const float* __restrict__ eb0,
    const float* __restrict__ e0g, const float* __restrict__ e0b,
    const float* __restrict__ e0m, const float* __restrict__ e0v,
    const float* __restrict__ eW1, const float* __restrict__ eb1,
    const float* __restrict__ e1g, const float* __restrict__ e1b,
    const float* __restrict__ e1m, const float* __restrict__ e1v,
    const float* __restrict__ eW2, const float* __restrict__ eb2,
    const float* __restrict__ e2g, const float* __restrict__ e2b,
    const float* __restrict__ e2m, const float* __restrict__ e2v,
    const float* __restrict__ oW, const float* __restrict__ ob,
    float* __restrict__ out)
{
  __shared__ SmemF sm;
  const int t = threadIdx.x;
  const int row0 = blockIdx.x * 16;
  {
    const int c = t;
    const float s  = in_g[c] * rsqrtf(in_v[c] + EPS);
    const float sh = in_b[c] - in_m[c] * s;
    #pragma unroll
    for (int r = 0; r < 16; ++r)
      sm.xn[r][c] = fmaf(x[(size_t)(row0 + r) * D + c], s, sh);
  }
  __syncthreads();
  {
    const int rg = t >> 6, c0 = (t & 63) * 2;
    float acc[4][2] = {};
    for (int k = 0; k < D; k += 4) {
      float4 xa[4];
      #pragma unroll
      for (int r = 0; r < 4; ++r) xa[r] = *(const float4*)(&sm.xn[rg * 4 + r][k]);
      float2 wv[4];
      #pragma unroll
      for (int kk = 0; kk < 4; ++kk) wv[kk] = *(const float2*)(&gW1[(size_t)(k + kk) * G + c0]);
      #pragma unroll
      for (int r = 0; r < 4; ++r) {
        const float* xv = (const float*)&xa[r];
        #pragma unroll
        for (int kk = 0; kk < 4; ++kk) {
          acc[r][0] = fmaf(xv[kk], wv[kk].x, acc[r][0]);
          acc[r][1] = fmaf(xv[kk], wv[kk].y, acc[r][1]);
        }
      }
    }
    #pragma unroll
    for (int j = 0; j < 2; ++j) {
      const int c = c0 + j;
      const float s  = g_g[c] * rsqrtf(g_v[c] + EPS);
      const float sh = fmaf(gb1[c] - g_m[c], s, g_b[c]);
      #pragma unroll
      for (int r = 0; r < 4; ++r)
        sm.h1[rg * 4 + r][c] = fmaxf(fmaf(acc[r][j], s, sh), 0.f);
    }
  }
  __syncthreads();
  if (t < 16 * NE) {
    const int r = t >> 3, e = t & 7;
    float acc = gb2[e];
    for (int k = 0; k < G; k += 4) {
      const float4 hv = *(const float4*)(&sm.h1[r][k]);
      acc = fmaf(hv.x, gW2[(k + 0) * NE + e], acc);
      acc = fmaf(hv.y, gW2[(k + 1) * NE + e], acc);
      acc = fmaf(hv.z, gW2[(k + 2) * NE + e], acc);
      acc = fmaf(hv.w, gW2[(k + 3) * NE + e], acc);
    }
    sm.gates[r][e] = acc;
  }
  __syncthreads();
  if (t < 16) {
    float v[NE]; float mx = -3.4e38f;
    #pragma unroll
    for (int e = 0; e < NE; ++e) { v[e] = sm.gates[t][e]; mx = fmaxf(mx, v[e]); }
    float ssum = 0.f;
    #pragma unroll
    for (int e = 0; e < NE; ++e) { v[e] = expf(v[e] - mx); ssum += v[e]; }
    const float inv = 1.f / ssum;
    #pragma unroll
    for (int e = 0; e < NE; ++e) sm.gates[t][e] = v[e] * inv;
  }
  __syncthreads();
  float comb[4] = {0.f, 0.f, 0.f, 0.f};
  const int rgA = t >> 6, c0A = (t & 63) * 4;
  const int rg1 = t >> 5, c01 = (t & 31) * 4;
  const int r2  = t >> 4, c02 = (t & 15) * 4;
  for (int e = 0; e < NE; ++e) {
    {
      const float* __restrict__ W = eW0 + (size_t)e * D * H0;
      float acc[4][4] = {};
      for (int k = 0; k < D; k += 4) {
        float4 xa[4];
        #pragma unroll
        for (int r = 0; r < 4; ++r) xa[r] = *(const float4*)(&sm.xn[rgA * 4 + r][k]);
        float4 wv[4];
        #pragma unroll
        for (int kk = 0; kk < 4; ++kk) wv[kk] = *(const float4*)(&W[(size_t)(k + kk) * H0 + c0A]);
        #pragma unroll
        for (int r = 0; r < 4; ++r) {
          const float* xv = (const float*)&xa[r];
          #pragma unroll
          for (int kk = 0; kk < 4; ++kk) {
            acc[r][0] = fmaf(xv[kk], wv[kk].x, acc[r][0]);
            acc[r][1] = fmaf(xv[kk], wv[kk].y, acc[r][1]);
            acc[r][2] = fmaf(xv[kk], wv[kk].z, acc[r][2]);
            acc[r][3] = fmaf(xv[kk], wv[kk].w, acc[r][3]);
          }
        }
      }
      const float4 gg = *(const float4*)(&e0g[e * H0 + c0A]);
      const float4 bb = *(const float4*)(&e0b[e * H0 + c0A]);
      const float4 mm = *(const float4*)(&e0m[e * H0 + c0A]);
      const float4 vv = *(const float4*)(&e0v[e * H0 + c0A]);
      const float4 bi = *(const float4*)(&eb0[e * H0 + c0A]);
      float s[4], sh[4];
      s[0] = gg.x * rsqrtf(vv.x + EPS); sh[0] = fmaf(bi.x - mm.x, s[0], bb.x);
      s[1] = gg.y * rsqrtf(vv.y + EPS); sh[1] = fmaf(bi.y - mm.y, s[1], bb.y);
      s[2] = gg.z * rsqrtf(vv.z + EPS); sh[2] = fmaf(bi.z - mm.z, s[2], bb.z);
      s[3] = gg.w * rsqrtf(vv.w + EPS); sh[3] = fmaf(bi.w - mm.w, s[3], bb.w);
      #pragma unroll
      for (int r = 0; r < 4; ++r) {
        float4 o;
        o.x = fmaxf(fmaf(acc[r][0], s[0], sh[0]), 0.f);
        o.y = fmaxf(fmaf(acc[r][1], s[1], sh[1]), 0.f);
        o.z = fmaxf(fmaf(acc[r][2], s[2], sh[2]), 0.f);
        o.w = fmaxf(fmaf(acc[r][3], s[3], sh[3]), 0.f);
        *(float4*)(&sm.h0[rgA * 4 + r][c0A]) = o;
      }
    }
    __syncthreads();
    {
      const float* __restrict__ W = eW1 + (size_t)e * H0 * H1;
      float acc[2][4] = {};
      for (int k = 0; k < H0; k += 4) {
        float4 xa[2];
        #pragma unroll
        for (int r = 0; r < 2; ++r) xa[r] = *(const float4*)(&sm.h0[rg1 * 2 + r][k]);
        float4 wv[4];
        #pragma unroll
        for (int kk = 0; kk < 4; ++kk) wv[kk] = *(const float4*)(&W[(size_t)(k + kk) * H1 + c01]);
        #pragma unroll
        for (int r = 0; r < 2; ++r) {
          const float* xv = (const float*)&xa[r];
          #pragma unroll
          for (int kk = 0; kk < 4; ++kk) {
            acc[r][0] = fmaf(xv[kk], wv[kk].x, acc[r][0]);
            acc[r][1] = fmaf(xv[kk], wv[kk].y, acc[r][1]);
            acc[r][2] = fmaf(xv[kk], wv[kk].z, acc[r][2]);
            acc[r][3] = fmaf(xv[kk], wv[kk].w, acc[r][3]);
          }
        }
      }
      const float4 gg = *(const float4*)(&e1g[e * H1 + c01]);
      const float4 bb = *(const float4*)(&e1b[e * H1 + c01]);
      const float4 mm = *(const float4*)(&e1m[e * H1 + c01]);
      const float4 vv = *(const float4*)(&e1v[e * H1 + c01]);
      const float4 bi = *(const float4*)(&eb1[e * H1 + c01]);
      float s[4], sh[4];
      s[0] = gg.x * rsqrtf(vv.x + EPS); sh[0] = fmaf(bi.x - mm.x, s[0], bb.x);
      s[1] = gg.y * rsqrtf(vv.y + EPS); sh[1] = fmaf(bi.y - mm.y, s[1], bb.y);
      s[2] = gg.z * rsqrtf(vv.z + EPS); sh[2] = fmaf(bi.z - mm.z, s[2], bb.z);
      s[3] = gg.w * rsqrtf(vv.w + EPS); sh[3] = fmaf(bi.w - mm.w, s[3], bb.w);
      #pragma unroll
      for (int r = 0; r < 2; ++r) {
        float4 o;
        o.x = fmaxf(fmaf(acc[r][0], s[0], sh[0]), 0.f);
        o.y = fmaxf(fmaf(acc[r][1], s[1], sh[1]), 0.f);
        o.z = fmaxf(fmaf(acc[r][2], s[2], sh[2]), 0.f);
        o.w = fmaxf(fmaf(acc[r][3], s[3], sh[3]), 0.f);
        *(float4*)(&sm.h1[rg1 * 2 + r][c01]) = o;
      }
    }
    __syncthreads();
    {
      const float* __restrict__ W = eW2 + (size_t)e * H1 * H2;
      float acc[4] = {};
      for (int k = 0; k < H1; k += 4) {
        const float4 xa = *(const float4*)(&sm.h1[r2][k]);
        const float4 w0 = *(const float4*)(&W[(size_t)(k + 0) * H2 + c02]);
        const float4 w1 = *(const float4*)(&W[(size_t)(k + 1) * H2 + c02]);
        const float4 w2 = *(const float4*)(&W[(size_t)(k + 2) * H2 + c02]);
        const float4 w3 = *(const float4*)(&W[(size_t)(k + 3) * H2 + c02]);
        acc[0] = fmaf(xa.x, w0.x, acc[0]); acc[1] = fmaf(xa.x, w0.y, acc[1]);
        acc[2] = fmaf(xa.x, w0.z, acc[2]); acc[3] = fmaf(xa.x, w0.w, acc[3]);
        acc[0] = fmaf(xa.y, w1.x, acc[0]); acc[1] = fmaf(xa.y, w1.y, acc[1]);
        acc[2] = fmaf(xa.y, w1.z, acc[2]); acc[3] = fmaf(xa.y, w1.w, acc[3]);
        acc[0] = fmaf(xa.z, w2.x, acc[0]); acc[1] = fmaf(xa.z, w2.y, acc[1]);
        acc[2] = fmaf(xa.z, w2.z, acc[2]); acc[3] = fmaf(xa.z, w2.w, acc[3]);
        acc[0] = fmaf(xa.w, w3.x, acc[0]); acc[1] = fmaf(xa.w, w3.y, acc[1]);
        acc[2] = fmaf(xa.w, w3.z, acc[2]); acc[3] = fmaf(xa.w, w3.w, acc[3]);
      }
      const float4 gg = *(const float4*)(&e2g[e * H2 + c02]);
      const float4 bb = *(const float4*)(&e2b[e * H2 + c02]);
      const float4 mm = *(const float4*)(&e2m[e * H2 + c02]);
      const float4 vv = *(const float4*)(&e2v[e * H2 + c02]);
      const float4 bi = *(const float4*)(&eb2[e * H2 + c02]);
      float s[4], sh[4];
      s[0] = gg.x * rsqrtf(vv.x + EPS); sh[0] = fmaf(bi.x - mm.x, s[0], bb.x);
      s[1] = gg.y * rsqrtf(vv.y + EPS); sh[1] = fmaf(bi.y - mm.y, s[1], bb.y);
      s[2] = gg.z * rsqrtf(vv.z + EPS); sh[2] = fmaf(bi.z - mm.z, s[2], bb.z);
      s[3] = gg.w * rsqrtf(vv.w + EPS); sh[3] = fmaf(bi.w - mm.w, s[3], bb.w);
      const float gate = sm.gates[r2][e];
      comb[0] = fmaf(gate, fmaxf(fmaf(acc[0], s[0], sh[0]), 0.f), comb[0]);
      comb[1] = fmaf(gate, fmaxf(fmaf(acc[1], s[1], sh[1]), 0.f), comb[1]);
      comb[2] = fmaf(gate, fmaxf(fmaf(acc[2], s[2], sh[2]), 0.f), comb[2]);
      comb[3] = fmaf(gate, fmaxf(fmaf(acc[3], s[3], sh[3]), 0.f), comb[3]);
    }
  }
  float part = comb[0] * oW[c02 + 0] + comb[1] * oW[c02 + 1] +
               comb[2] * oW[c02 + 2] + comb[3] * oW[c02 + 3];
  part += __shfl_xor(part, 1);
  part += __shfl_xor(part, 2);
  part += __shfl_xor(part, 4);
  part += __shfl_xor(part, 8);
  if ((t & 15) == 0) out[row0 + r2] = part + ob[0];
}

// ------------------------------------------------------------------ launch --
extern "C" void kernel_launch(void* const* d_in, const int* in_sizes, int n_in,
                              void* d_out, int out_size, void* d_ws, size_t ws_size,
                              hipStream_t stream) {
  const float* x    = (const float*)d_in[0];
  const float* in_g = (const float*)d_in[1];
  const float* in_b = (const float*)d_in[2];
  const float* in_m = (const float*)d_in[3];
  const float* in_v = (const float*)d_in[4];
  const float* gW1  = (const float*)d_in[5];
  const float* gb1  = (const float*)d_in[6];
  const float* g_g  = (const float*)d_in[7];
  const float* g_b  = (const float*)d_in[8];
  const float* g_m  = (const float*)d_in[9];
  const float* g_v  = (const float*)d_in[10];
  const float* gW2  = (const float*)d_in[11];
  const float* gb2  = (const float*)d_in[12];
  const float* eW0  = (const float*)d_in[13];
  const float* eb0  = (const float*)d_in[14];
  const float* e0g  = (const float*)d_in[15];
  const float* e0b  = (const float*)d_in[16];
  const float* e0m  = (const float*)d_in[17];
  const float* e0v  = (const float*)d_in[18];
  const float* eW1  = (const float*)d_in[19];
  const float* eb1  = (const float*)d_in[20];
  const float* e1g  = (const float*)d_in[21];
  const float* e1b  = (const float*)d_in[22];
  const float* e1m  = (const float*)d_in[23];
  const float* e1v  = (const float*)d_in[24];
  const float* eW2  = (const float*)d_in[25];
  const float* eb2  = (const float*)d_in[26];
  const float* e2g  = (const float*)d_in[27];
  const float* e2b  = (const float*)d_in[28];
  const float* e2m  = (const float*)d_in[29];
  const float* e2v  = (const float*)d_in[30];
  const float* oW   = (const float*)d_in[31];
  const float* ob   = (const float*)d_in[32];
  float* out = (float*)d_out;
  const int Btot = in_sizes[0] / D;

  if (ws_size >= WS_BYTES && (Btot % TBR) == 0) {
    u16* ws = (u16*)d_ws;
    repack_w<<<TP_TOTAL / 4, 256, 0, stream>>>(eW0, eW1, eW2, gW1, gW2, ws);
    moe_mfma<<<Btot / TBR, NT, 0, stream>>>(
        x, in_g, in_b, in_m, in_v,
        gb1, g_g, g_b, g_m, g_v, gb2,
        eb0, e0g, e0b, e0m, e0v,
        eb1, e1g, e1b, e1m, e1v,
        eb2, e2g, e2b, e2m, e2v,
        oW, ob, ws, out);
  } else {
    moe_fused_fp32<<<Btot / 16, 256, 0, stream>>>(
        x, in_g, in_b, in_m, in_v,
        gW1, gb1, g_g, g_b, g_m, g_v, gW2, gb2,
        eW0, eb0, e0g, e0b, e0m, e0v,
        eW1, eb1, e1g, e1b, e1m, e1v,
        eW2, eb2, e2g, e2b, e2m, e2v,
        oW, ob, out);
  }
}

// Round 13
// 321.495 us; speedup vs baseline: 1.0897x; 1.0897x over previous
//
#include <hip/hip_runtime.h>
#include <hip/hip_bf16.h>

#define D   256
#define NE  8
#define G   128
#define H0  256
#define H1  128
#define H2  64
#define TBR 64
#define NT  256
#define EPS 1e-5f

typedef unsigned short u16;
typedef __attribute__((ext_vector_type(8))) short bf16x8;
typedef __attribute__((ext_vector_type(4))) float f32x4;
typedef __attribute__((ext_vector_type(4))) unsigned short u16x4;

#define MFMA16(a,b,c) __builtin_amdgcn_mfma_f32_16x16x32_bf16((a),(b),(c),0,0,0)

// ws layout: tile-pairs of 1024 u16 (512 hi + 512 lo), wave-fragment order:
// lane l holds B[k = kt*32 + 8*(l>>4) + j][n = nt*16 + (l&15)], j=0..7.
// EXPERT tiles: hi = RNE-rounded bf16 (1-term consumption, lo unused).
// GATING tiles: hi = truncated, lo = remainder (2-term consumption).
#define TP_EW0 1024   // 8e * 16nt * 8kt
#define TP_EW1 512    // 8e * 8nt * 8kt
#define TP_EW2 128    // 8e * 4nt * 4kt
#define TP_GW1 64     // 8nt * 8kt
#define TP_GW2 4      // 1nt(padded 16 cols) * 4kt
#define TPO_EW1 (TP_EW0)
#define TPO_EW2 (TP_EW0 + TP_EW1)
#define TPO_GW1 (TP_EW0 + TP_EW1 + TP_EW2)
#define TPO_GW2 (TPO_GW1 + TP_GW1)
#define TP_TOTAL (TPO_GW2 + TP_GW2)
#define WS_BYTES ((size_t)TP_TOTAL * 2048)

__device__ __forceinline__ u16 rne_bf16(float v) {
  unsigned u = __float_as_uint(v);
  u += 0x7FFFu + ((u >> 16) & 1u);
  return (u16)(u >> 16);
}

// ---------------------------------------------------------------- repack ----
__global__ __launch_bounds__(256) void repack_w(
    const float* __restrict__ eW0, const float* __restrict__ eW1,
    const float* __restrict__ eW2, const float* __restrict__ gW1,
    const float* __restrict__ gW2, u16* __restrict__ ws)
{
  const int wid = (blockIdx.x * 256 + threadIdx.x) >> 6;
  const int l   = threadIdx.x & 63;
  if (wid >= TP_TOTAL) return;
  const float* src; int ncols, nt, kt; bool pad8 = false;
  const bool expert = (wid < TPO_GW1);   // expert tiles: 1-term RNE
  if (wid < TP_EW0) {
    int e = wid >> 7, r = wid & 127; nt = r >> 3; kt = r & 7;
    src = eW0 + (size_t)e * D * H0; ncols = H0;
  } else if (wid < TPO_EW2) {
    int w2 = wid - TPO_EW1; int e = w2 >> 6, r = w2 & 63; nt = r >> 3; kt = r & 7;
    src = eW1 + (size_t)e * H0 * H1; ncols = H1;
  } else if (wid < TPO_GW1) {
    int w3 = wid - TPO_EW2; int e = w3 >> 4, r = w3 & 15; nt = r >> 2; kt = r & 3;
    src = eW2 + (size_t)e * H1 * H2; ncols = H2;
  } else if (wid < TPO_GW2) {
    int w4 = wid - TPO_GW1; nt = w4 >> 3; kt = w4 & 7;
    src = gW1; ncols = G;
  } else {
    kt = wid - TPO_GW2; nt = 0;
    src = gW2; ncols = NE; pad8 = true;   // pad cols 8..15 with zeros
  }
  const int n  = nt * 16 + (l & 15);
  const int k0 = kt * 32 + 8 * (l >> 4);
  u16 hi[8], lo[8];
  #pragma unroll
  for (int j = 0; j < 8; ++j) {
    float v = (pad8 && (l & 15) >= 8) ? 0.f : src[(size_t)(k0 + j) * ncols + (pad8 ? (n & 7) : n)];
    if (expert) {
      hi[j] = rne_bf16(v);    // 1-term: round-to-nearest
      lo[j] = 0;
    } else {
      unsigned u = __float_as_uint(v);
      hi[j] = (u16)(u >> 16);
      float hf = __uint_as_float(u & 0xFFFF0000u);
      lo[j] = (u16)(__float_as_uint(v - hf) >> 16);
    }
  }
  u16* dst = ws + (size_t)wid * 1024 + l * 8;
  *(u16x4*)(dst + 0)       = u16x4{hi[0], hi[1], hi[2], hi[3]};
  *(u16x4*)(dst + 4)       = u16x4{hi[4], hi[5], hi[6], hi[7]};
  *(u16x4*)(dst + 512 + 0) = u16x4{lo[0], lo[1], lo[2], lo[3]};
  *(u16x4*)(dst + 512 + 4) = u16x4{lo[4], lo[5], lo[6], lo[7]};
}

// ------------------------------------------------------------- main MFMA ----
struct Smem {
  u16 xnh[TBR * D];   // 32 KiB, persistent
  u16 h0h[TBR * H0];  // 32 KiB (gating hidden gh in cols 0..127 pre-experts)
  union {
    u16 h1h[TBR * H1];    // 16 KiB (experts)
    float ss[2][D];       // Phase A/B only
    float part[2][2][32]; // final reduction only
  } u;
};                        // total 81920 B -> TWO blocks/CU (160 KiB LDS)

__device__ __forceinline__ int swz512(int r, int c) {
  return (r * 512 + ((c * 2) ^ ((r & 7) << 4))) >> 1;   // u16 index, row stride 512B
}
__device__ __forceinline__ int swz256(int r, int c) {
  return (r * 256 + ((c * 2) ^ ((r & 7) << 4))) >> 1;   // u16 index, row stride 256B
}
__device__ __forceinline__ bf16x8 ldA(const u16* p, int idx) {
  return *(const bf16x8*)(p + idx);
}

// 4-wave blocks, 80 KiB LDS -> 2 independent blocks/CU (barrier overlap,
// m114 mechanism) with the FULL 256-reg/wave budget at (256,2): 2 waves/EU
// x 4 EU / 4 waves-per-block = 2 blocks/CU. R4/R6's spills came from the
// (512,4) 64-VGPR split; this keeps 2 waves/SIMD so ~100-reg loops fit.
// R11 bug fixed: Phase B j-loop must cover D=256 cols (4 thr/row x 16 x 4).
__global__ __launch_bounds__(NT, 2) void moe_mfma(
    const float* __restrict__ x,
    const float* __restrict__ in_g, const float* __restrict__ in_b,
    const float* __restrict__ in_m, const float* __restrict__ in_v,
    const float* __restrict__ gb1,
    const float* __restrict__ g_g, const float* __restrict__ g_b,
    const float* __restrict__ g_m, const float* __restrict__ g_v,
    const float* __restrict__ gb2,
    const float* __restrict__ eb0,
    const float* __restrict__ e0g, const float* __restrict__ e0b,
    const float* __restrict__ e0m, const float* __restrict__ e0v,
    const float* __restrict__ eb1,
    const float* __restrict__ e1g, const float* __restrict__ e1b,
    const float* __restrict__ e1m, const float* __restrict__ e1v,
    const float* __restrict__ eb2,
    const float* __restrict__ e2g, const float* __restrict__ e2b,
    const float* __restrict__ e2m, const float* __restrict__ e2v,
    const float* __restrict__ oW, const float* __restrict__ ob,
    const u16* __restrict__ ws, float* __restrict__ out)
{
  __shared__ Smem sm;
  const int t = threadIdx.x;
  const int l = t & 63;
  const int w = t >> 6;            // wave 0..3
  const int row0 = blockIdx.x * TBR;
  const int rA  = l & 15;
  const int kg8 = 8 * (l >> 4);
  const int lg4 = (l >> 4) * 4;
  const int wg  = w >> 1;          // L2 / gating m-group (m-tiles 2wg, 2wg+1)
  const int np  = w & 1;           // L2 n-pair

  // ---- Phase A: input-BN scale/shift -> LDS (u region, dead until experts)
  if (t < D) {
    float s = in_g[t] * rsqrtf(in_v[t] + EPS);
    sm.u.ss[0][t] = s;
    sm.u.ss[1][t] = in_b[t] - in_m[t] * s;
  }
  __syncthreads();

  // ---- Phase B: load x, BN, RNE bf16 -> xnh (swizzled); 64 rows x 256 cols
  // 4 threads/row x 16 j-iters x 4 floats = 256 cols (R11 bug: j<8 = half).
  {
    const int row = t >> 2;
    #pragma unroll
    for (int j = 0; j < 16; ++j) {
      const int cb = ((t & 3) + j * 4) * 4;
      const float4 xv = *(const float4*)(x + (size_t)(row0 + row) * D + cb);
      u16 h4[4];
      #pragma unroll
      for (int q = 0; q < 4; ++q) {
        float val = fmaf(((const float*)&xv)[q], sm.u.ss[0][cb + q], sm.u.ss[1][cb + q]);
        h4[q] = rne_bf16(val);
      }
      *(u16x4*)(sm.xnh + swz512(row, cb)) = u16x4{h4[0], h4[1], h4[2], h4[3]};
    }
  }
  __syncthreads();

  // ---- Phase C: gating hidden gh = relu(bn(xn@gW1+gb1)) -> h0h cols 0..127
  // wave w -> n-tiles {2w, 2w+1}, all 4 m-tiles (2-term exact gW1)
  {
    f32x4 acc[4][2] = {};
    #pragma unroll
    for (int kt = 0; kt < 8; ++kt) {
      bf16x8 ah[4];
      #pragma unroll
      for (int mi = 0; mi < 4; ++mi)
        ah[mi] = ldA(sm.xnh, swz512(mi * 16 + rA, kt * 32 + kg8));
      #pragma unroll
      for (int ni = 0; ni < 2; ++ni) {
        const size_t tp = (size_t)TPO_GW1 + (size_t)(w * 2 + ni) * 8 + kt;
        const bf16x8 wh = *((const bf16x8*)(ws + tp * 1024) + l);
        const bf16x8 wl = *((const bf16x8*)(ws + tp * 1024 + 512) + l);
        #pragma unroll
        for (int mi = 0; mi < 4; ++mi) {
          acc[mi][ni] = MFMA16(ah[mi], wh, acc[mi][ni]);
          acc[mi][ni] = MFMA16(ah[mi], wl, acc[mi][ni]);
        }
      }
    }
    #pragma unroll
    for (int ni = 0; ni < 2; ++ni) {
      const int c = (w * 2 + ni) * 16 + rA;
      const float s  = g_g[c] * rsqrtf(g_v[c] + EPS);
      const float sh = fmaf(gb1[c] - g_m[c], s, g_b[c]);
      #pragma unroll
      for (int mi = 0; mi < 4; ++mi)
        #pragma unroll
        for (int r = 0; r < 4; ++r)
          sm.h0h[swz512(mi * 16 + lg4 + r, c)] =
              rne_bf16(fmaxf(fmaf(acc[mi][ni][r], s, sh), 0.f));
    }
  }
  __syncthreads();

  // ---- Phase D: gate logits via MFMA (padded gW2), in-register softmax
  // wave computes gates for m-tiles {2wg, 2wg+1} (matches its L2 rows)
  f32x4 gmine[2];  // gate[row=(2wg+mi)*16+lg4+r][expert=rA], rA<8 valid
  #pragma unroll
  for (int mi = 0; mi < 2; ++mi) {
    f32x4 acc = {};
    #pragma unroll
    for (int kt = 0; kt < 4; ++kt) {
      const bf16x8 ah = ldA(sm.h0h, swz512((2 * wg + mi) * 16 + rA, kt * 32 + kg8));
      const size_t tp = (size_t)TPO_GW2 + kt;
      const bf16x8 wh = *((const bf16x8*)(ws + tp * 1024) + l);
      const bf16x8 wl = *((const bf16x8*)(ws + tp * 1024 + 512) + l);
      acc = MFMA16(ah, wh, acc);
      acc = MFMA16(ah, wl, acc);
    }
    #pragma unroll
    for (int r = 0; r < 4; ++r) {
      float v = (rA < 8) ? (acc[r] + gb2[rA]) : -3.4e38f;
      float mx = v;
      mx = fmaxf(mx, __shfl_xor(mx, 1));
      mx = fmaxf(mx, __shfl_xor(mx, 2));
      mx = fmaxf(mx, __shfl_xor(mx, 4));
      mx = fmaxf(mx, __shfl_xor(mx, 8));
      float p = expf(v - mx);          // -inf lanes -> 0
      float ssum = p;
      ssum += __shfl_xor(ssum, 1);
      ssum += __shfl_xor(ssum, 2);
      ssum += __shfl_xor(ssum, 4);
      ssum += __shfl_xor(ssum, 8);
      gmine[mi][r] = p / ssum;
    }
  }
  __syncthreads();

  // ---- Phase E: experts (2 barriers per expert); 1-term RNE weights
  f32x4 comb[2][2] = {};   // [mi][nti]
  for (int e = 0; e < NE; ++e) {
    // L0: h0 = relu(bn(xn @ eW0[e] + eb0));
    // wave w -> n-tiles w*4..w*4+3 (two acc[4][2] passes), all 4 m-tiles
    #pragma unroll
    for (int half = 0; half < 2; ++half) {
      f32x4 acc[4][2] = {};
      #pragma unroll
      for (int kt = 0; kt < 8; ++kt) {
        bf16x8 ah[4];
        #pragma unroll
        for (int mi = 0; mi < 4; ++mi)
          ah[mi] = ldA(sm.xnh, swz512(mi * 16 + rA, kt * 32 + kg8));
        #pragma unroll
        for (int ni = 0; ni < 2; ++ni) {
          const size_t tp = ((size_t)e * 16 + w * 4 + half * 2 + ni) * 8 + kt;
          const bf16x8 wh = *((const bf16x8*)(ws + tp * 1024) + l);
          #pragma unroll
          for (int mi = 0; mi < 4; ++mi)
            acc[mi][ni] = MFMA16(ah[mi], wh, acc[mi][ni]);
        }
      }
      #pragma unroll
      for (int ni = 0; ni < 2; ++ni) {
        const int c = (w * 4 + half * 2 + ni) * 16 + rA;
        const float s  = e0g[e * H0 + c] * rsqrtf(e0v[e * H0 + c] + EPS);
        const float sh = fmaf(eb0[e * H0 + c] - e0m[e * H0 + c], s, e0b[e * H0 + c]);
        #pragma unroll
        for (int mi = 0; mi < 4; ++mi)
          #pragma unroll
          for (int r = 0; r < 4; ++r)
            sm.h0h[swz512(mi * 16 + lg4 + r, c)] =
                rne_bf16(fmaxf(fmaf(acc[mi][ni][r], s, sh), 0.f));
      }
    }
    __syncthreads();
    // L1: h1 = relu(bn(h0 @ eW1[e] + eb1));
    // wave w -> n-tiles {2w, 2w+1}, all 4 m-tiles
    {
      f32x4 acc[4][2] = {};
      #pragma unroll
      for (int kt = 0; kt < 8; ++kt) {
        bf16x8 ah[4];
        #pragma unroll
        for (int mi = 0; mi < 4; ++mi)
          ah[mi] = ldA(sm.h0h, swz512(mi * 16 + rA, kt * 32 + kg8));
        #pragma unroll
        for (int ni = 0; ni < 2; ++ni) {
          const size_t tp = TPO_EW1 + ((size_t)e * 8 + w * 2 + ni) * 8 + kt;
          const bf16x8 wh = *((const bf16x8*)(ws + tp * 1024) + l);
          #pragma unroll
          for (int mi = 0; mi < 4; ++mi)
            acc[mi][ni] = MFMA16(ah[mi], wh, acc[mi][ni]);
        }
      }
      #pragma unroll
      for (int ni = 0; ni < 2; ++ni) {
        const int c = (w * 2 + ni) * 16 + rA;
        const float s  = e1g[e * H1 + c] * rsqrtf(e1v[e * H1 + c] + EPS);
        const float sh = fmaf(eb1[e * H1 + c] - e1m[e * H1 + c], s, e1b[e * H1 + c]);
        #pragma unroll
        for (int mi = 0; mi < 4; ++mi)
          #pragma unroll
          for (int r = 0; r < 4; ++r)
            sm.u.h1h[swz256(mi * 16 + lg4 + r, c)] =
                rne_bf16(fmaxf(fmaf(acc[mi][ni][r], s, sh), 0.f));
      }
    }
    __syncthreads();
    // L2 + gated combine (h2 stays in registers);
    // wave -> m-tiles {2wg, 2wg+1}, n-tiles {2np, 2np+1}
    #pragma unroll
    for (int nti = 0; nti < 2; ++nti) {
      f32x4 acc2[2] = {};
      #pragma unroll
      for (int kt = 0; kt < 4; ++kt) {
        const size_t tp = TPO_EW2 + ((size_t)e * 4 + 2 * np + nti) * 4 + kt;
        const bf16x8 wh = *((const bf16x8*)(ws + tp * 1024) + l);
        #pragma unroll
        for (int mi = 0; mi < 2; ++mi) {
          const bf16x8 ah = ldA(sm.u.h1h, swz256((2 * wg + mi) * 16 + rA, kt * 32 + kg8));
          acc2[mi] = MFMA16(ah, wh, acc2[mi]);
        }
      }
      const int c = (2 * np + nti) * 16 + rA;
      const float s  = e2g[e * H2 + c] * rsqrtf(e2v[e * H2 + c] + EPS);
      const float sh = fmaf(eb2[e * H2 + c] - e2m[e * H2 + c], s, e2b[e * H2 + c]);
      #pragma unroll
      for (int mi = 0; mi < 2; ++mi)
        #pragma unroll
        for (int r = 0; r < 4; ++r) {
          const float gt = __shfl(gmine[mi][r], (l & 48) | e);  // gate[row][e]
          comb[mi][nti][r] = fmaf(gt, fmaxf(fmaf(acc2[mi][r], s, sh), 0.f),
                                  comb[mi][nti][r]);
        }
    }
    // hazard-free: h0h rewritten only after post-L1 barrier of this expert;
    // h1h rewritten only after post-L0 barrier of next expert.
  }

  // ---- Phase F: out = comb @ oW + ob (part aliases h1h -> barrier first)
  const float w0 = oW[(2 * np + 0) * 16 + rA];
  const float w1 = oW[(2 * np + 1) * 16 + rA];
  __syncthreads();
  #pragma unroll
  for (int mi = 0; mi < 2; ++mi)
    #pragma unroll
    for (int r = 0; r < 4; ++r) {
      float sx = comb[mi][0][r] * w0 + comb[mi][1][r] * w1;
      sx += __shfl_xor(sx, 1);
      sx += __shfl_xor(sx, 2);
      sx += __shfl_xor(sx, 4);
      sx += __shfl_xor(sx, 8);
      if (rA == 0) sm.u.part[wg][np][mi * 16 + lg4 + r] = sx;
    }
  __syncthreads();
  if (t < TBR)
    out[row0 + t] = sm.u.part[t >> 5][0][t & 31] +
                    sm.u.part[t >> 5][1][t & 31] + ob[0];
}

// ------------------------------------------------- fp32 fallback (verified) -
struct SmemF {
  float xn[16][D]; float h0[16][H0]; float h1[16][H1]; float gates[16][NE];
};
__global__ __launch_bounds__(256, 2) void moe_fused_fp32(
    const float* __restrict__ x,
    const float* __restrict__ in_g, const float* __restrict__ in_b,
    const float* __restrict__ in_m, const float* __restrict__ in_v,
    const float* __restrict__ gW1, const float* __restrict__ gb1,
    const float* __restrict__ g_g, const float* __restrict__ g_b,
    const float* __restrict__ g_m, const float* __restrict__ g_v,
    const float* __restrict__ gW2, const float* __restrict__ gb2,
    const float* __restrict__ eW0, const float* __restrict__ eb0,
    const float* __restrict__ e0g, const float* __restrict__ e0b,
    const float* __restrict__ e0m, const float* __restrict__ e0v,
    const float* __restrict__ eW1, const float* __restrict__ eb1,
    const float* __restrict__ e1g, const float* __restrict__ e1b,
    const float* __restrict__ e1m, const float* __restrict__ e1v,
    const float* __restrict__ eW2, const float* __restrict__ eb2,
    const float* __restrict__ e2g, const float* __restrict__ e2b,
    const float* __restrict__ e2m, const float* __restrict__ e2v,
    const float* __restrict__ oW, const float* __restrict__ ob,
    float* __restrict__ out)
{
  __shared__ SmemF sm;
  const int t = threadIdx.x;
  const int row0 = blockIdx.x * 16;
  {
    const int c = t;
    const float s  = in_g[c] * rsqrtf(in_v[c] + EPS);
    const float sh = in_b[c] - in_m[c] * s;
    #pragma unroll
    for (int r = 0; r < 16; ++r)
      sm.xn[r][c] = fmaf(x[(size_t)(row0 + r) * D + c], s, sh);
  }
  __syncthreads();
  {
    const int rg = t >> 6, c0 = (t & 63) * 2;
    float acc[4][2] = {};
    for (int k = 0; k < D; k += 4) {
      float4 xa[4];
      #pragma unroll
      for (int r = 0; r < 4; ++r) xa[r] = *(const float4*)(&sm.xn[rg * 4 + r][k]);
      float2 wv[4];
      #pragma unroll
      for (int kk = 0; kk < 4; ++kk) wv[kk] = *(const float2*)(&gW1[(size_t)(k + kk) * G + c0]);
      #pragma unroll
      for (int r = 0; r < 4; ++r) {
        const float* xv = (const float*)&xa[r];
        #pragma unroll
        for (int kk = 0; kk < 4; ++kk) {
          acc[r][0] = fmaf(xv[kk], wv[kk].x, acc[r][0]);
          acc[r][1] = fmaf(xv[kk], wv[kk].y, acc[r][1]);
        }
      }
    }
    #pragma unroll
    for (int j = 0; j < 2; ++j) {
      const int c = c0 + j;
      const float s  = g_g[c] * rsqrtf(g_v[c] + EPS);
      const float sh = fmaf(gb1[c] - g_m[c], s, g_b[c]);
      #pragma unroll
      for (int r = 0; r < 4; ++r)
        sm.h1[rg * 4 + r][c] = fmaxf(fmaf(acc[r][j], s, sh), 0.f);
    }
  }
  __syncthreads();
  if (t < 16 * NE) {
    const int r = t >> 3, e = t & 7;
    float acc = gb2[e];
    for (int k = 0; k < G; k += 4) {
      const float4 hv = *(const float4*)(&sm.h1[r][k]);
      acc = fmaf(hv.x, gW2[(k + 0) * NE + e], acc);
      acc = fmaf(hv.y, gW2[(k + 1) * NE + e], acc);
      acc = fmaf(hv.z, gW2[(k + 2) * NE + e], acc);
      acc = fmaf(hv.w, gW2[(k + 3) * NE + e], acc);
    }
    sm.gates[r][e] = acc;
  }
  __syncthreads();
  if (t < 16) {
    float v[NE]; float mx = -3.4e38f;
    #pragma unroll
    for (int e = 0; e < NE; ++e) { v[e] = sm.gates[t][e]; mx = fmaxf(mx, v[e]); }
    float ssum = 0.f;
    #pragma unroll
    for (int e = 0; e < NE; ++e) { v[e] = expf(v[e] - mx); ssum += v[e]; }
    const float inv = 1.f / ssum;
    #pragma unroll
    for (int e = 0; e < NE; ++e) sm.gates[t][e] = v[e] * inv;
  }
  __syncthreads();
  float comb[4] = {0.f, 0.f, 0.f, 0.f};
  const int rgA = t >> 6, c0A = (t & 63) * 4;
  const int rg1 = t >> 5, c01 = (t & 31) * 4;
  const int r2  = t >> 4, c02 = (t & 15) * 4;
  for (int e = 0; e < NE; ++e) {
    {
      const float* __restrict__ W = eW0 + (size_t)e * D * H0;
      float acc[4][4] = {};
      for (int k = 0; k < D; k += 4) {
        float4 xa[4];
        #pragma unroll
        for (int r = 0; r < 4; ++r) xa[r] = *(const float4*)(&sm.xn[rgA * 4 + r][k]);
        float4 wv[4];
        #pragma unroll
        for (int kk = 0; kk < 4; ++kk) wv[kk] = *(const float4*)(&W[(size_t)(k + kk) * H0 + c0A]);
        #pragma unroll
        for (int r = 0; r < 4; ++r) {
          const float* xv = (const float*)&xa[r];
          #pragma unroll
          for (int kk = 0; kk < 4; ++kk) {
            acc[r][0] = fmaf(xv[kk], wv[kk].x, acc[r][0]);
            acc[r][1] = fmaf(xv[kk], wv[kk].y, acc[r][1]);
            acc[r][2] = fmaf(xv[kk], wv[kk].z, acc[r][2]);
            acc[r][3] = fmaf(xv[kk], wv[kk].w, acc[r][3]);
          }
        }
      }
      const float4 gg = *(const float4*)(&e0g[e * H0 + c0A]);
      const float4 bb = *(const float4*)(&e0b[e * H0 + c0A]);
      const float4 mm = *(const float4*)(&e0m[e * H0 + c0A]);
      const float4 vv = *(const float4*)(&e0v[e * H0 + c0A]);
      const float4 bi = *(const float4*)(&eb0[e * H0 + c0A]);
      float s[4], sh[4];
      s[0] = gg.x * rsqrtf(vv.x + EPS); sh[0] = fmaf(bi.x - mm.x, s[0], bb.x);
      s[1] = gg.y * rsqrtf(vv.y + EPS); sh[1] = fmaf(bi.y - mm.y, s[1], bb.y);
      s[2] = gg.z * rsqrtf(vv.z + EPS); sh[2] = fmaf(bi.z - mm.z, s[2], bb.z);
      s[3] = gg.w * rsqrtf(vv.w + EPS); sh[3] = fmaf(bi.w - mm.w, s[3], bb.w);
      #pragma unroll
      for (int r = 0; r < 4; ++r) {
        float4 o;
        o.x = fmaxf(fmaf(acc[r][0], s[0], sh[0]), 0.f);
        o.y = fmaxf(fmaf(acc[r][1], s[1], sh[1]), 0.f);
        o.z = fmaxf(fmaf(acc[r][2], s[2], sh[2]), 0.f);
        o.w = fmaxf(fmaf(acc[r][3], s[3], sh[3]), 0.f);
        *(float4*)(&sm.h0[rgA * 4 + r][c0A]) = o;
      }
    }
    __syncthreads();
    {
      const float* __restrict__ W = eW1 + (size_t)e * H0 * H1;
      float acc[2][4] = {};
      for (int k = 0; k < H0; k += 4) {
        float4 xa[2];
        #pragma unroll
        for (int r = 0; r < 2; ++r) xa[r] = *(const float4*)(&sm.h0[rg1 * 2 + r][k]);
        float4 wv[4];
        #pragma unroll
        for (int kk = 0; kk < 4; ++kk) wv[kk] = *(const float4*)(&W[(size_t)(k + kk) * H1 + c01]);
        #pragma unroll
        for (int r = 0; r < 2; ++r) {
          const float* xv = (const float*)&xa[r];
          #pragma unroll
          for (int kk = 0; kk < 4; ++kk) {
            acc[r][0] = fmaf(xv[kk], wv[kk].x, acc[r][0]);
            acc[r][1] = fmaf(xv[kk], wv[kk].y, acc[r][1]);
            acc[r][2] = fmaf(xv[kk], wv[kk].z, acc[r][2]);
            acc[r][3] = fmaf(xv[kk], wv[kk].w, acc[r][3]);
          }
        }
      }
      const float4 gg = *(const float4*)(&e1g[e * H1 + c01]);
      const float4 bb = *(const float4*)(&e1b[e * H1 + c01]);
      const float4 mm = *(const float4*)(&e1m[e * H1 + c01]);
      const float4 vv = *(const float4*)(&e1v[e * H1 + c01]);
      const float4 bi = *(const float4*)(&eb1[e * H1 + c01]);
      float s[4], sh[4];
      s[0] = gg.x * rsqrtf(vv.x + EPS); sh[0] = fmaf(bi.x - mm.x, s[0], bb.x);
      s[1] = gg.y * rsqrtf(vv.y + EPS); sh[1] = fmaf(bi.y - mm.y, s[1], bb.y);
      s[2] = gg.z * rsqrtf(vv.z + EPS); sh[2] = fmaf(bi.z - mm.z, s[2], bb.z);
      s[3] = gg.w * rsqrtf(vv.w + EPS); sh[3] = fmaf(bi.w - mm.w, s[3], bb.w);
      #pragma unroll
      for (int r = 0; r < 2; ++r) {
        float4 o;
        o.x = fmaxf(fmaf(acc[r][0], s[0], sh[0]), 0.f);
        o.y = fmaxf(fmaf(acc[r][1], s[1], sh[1]), 0.f);
        o.z = fmaxf(fmaf(acc[r][2], s[2], sh[2]), 0.f);
        o.w = fmaxf(fmaf(acc[r][3], s[3], sh[3]), 0.f);
        *(float4*)(&sm.h1[rg1 * 2 + r][c01]) = o;
      }
    }
    __syncthreads();
    {
      const float* __restrict__ W = eW2 + (size_t)e * H1 * H2;
      float acc[4] = {};
      for (int k = 0; k < H1; k += 4) {
        const float4 xa = *(const float4*)(&sm.h1[r2][k]);
        const float4 w0 = *(const float4*)(&W[(size_t)(k + 0) * H2 + c02]);
        const float4 w1 = *(const float4*)(&W[(size_t)(k + 1) * H2 + c02]);
        const float4 w2 = *(const float4*)(&W[(size_t)(k + 2) * H2 + c02]);
        const float4 w3 = *(const float4*)(&W[(size_t)(k + 3) * H2 + c02]);
        acc[0] = fmaf(xa.x, w0.x, acc[0]); acc[1] = fmaf(xa.x, w0.y, acc[1]);
        acc[2] = fmaf(xa.x, w0.z, acc[2]); acc[3] = fmaf(xa.x, w0.w, acc[3]);
        acc[0] = fmaf(xa.y, w1.x, acc[0]); acc[1] = fmaf(xa.y, w1.y, acc[1]);
        acc[2] = fmaf(xa.y, w1.z, acc[2]); acc[3] = fmaf(xa.y, w1.w, acc[3]);
        acc[0] = fmaf(xa.z, w2.x, acc[0]); acc[1] = fmaf(xa.z, w2.y, acc[1]);
        acc[2] = fmaf(xa.z, w2.z, acc[2]); acc[3] = fmaf(xa.z, w2.w, acc[3]);
        acc[0] = fmaf(xa.w, w3.x, acc[0]); acc[1] = fmaf(xa.w, w3.y, acc[1]);
        acc[2] = fmaf(xa.w, w3.z, acc[2]); acc[3] = fmaf(xa.w, w3.w, acc[3]);
      }
      const float4 gg = *(const float4*)(&e2g[e * H2 + c02]);
      const float4 bb = *(const float4*)(&e2b[e * H2 + c02]);
      const float4 mm = *(const float4*)(&e2m[e * H2 + c02]);
      const float4 vv = *(const float4*)(&e2v[e * H2 + c02]);
      const float4 bi = *(const float4*)(&eb2[e * H2 + c02]);
      float s[4], sh[4];
      s[0] = gg.x * rsqrtf(vv.x + EPS); sh[0] = fmaf(bi.x - mm.x, s[0], bb.x);
      s[1] = gg.y * rsqrtf(vv.y + EPS); sh[1] = fmaf(bi.y - mm.y, s[1], bb.y);
      s[2] = gg.z * rsqrtf(vv.z + EPS); sh[2] = fmaf(bi.z - mm.z, s[2], bb.z);
      s[3] = gg.w * rsqrtf(vv.w + EPS); sh[3] = fmaf(bi.w - mm.w, s[3], bb.w);
      const float gate = sm.gates[r2][e];
      comb[0] = fmaf(gate, fmaxf(fmaf(acc[0], s[0], sh[0]), 0.f), comb[0]);
      comb[1] = fmaf(gate, fmaxf(fmaf(acc[1], s[1], sh[1]), 0.f), comb[1]);
      comb[2] = fmaf(gate, fmaxf(fmaf(acc[2], s[2], sh[2]), 0.f), comb[2]);
      comb[3] = fmaf(gate, fmaxf(fmaf(acc[3], s[3], sh[3]), 0.f), comb[3]);
    }
  }
  float part = comb[0] * oW[c02 + 0] + comb[1] * oW[c02 + 1] +
               comb[2] * oW[c02 + 2] + comb[3] * oW[c02 + 3];
  part += __shfl_xor(part, 1);
  part += __shfl_xor(part, 2);
  part += __shfl_xor(part, 4);
  part += __shfl_xor(part, 8);
  if ((t & 15) == 0) out[row0 + r2] = part + ob[0];
}

// ------------------------------------------------------------------ launch --
extern "C" void kernel_launch(void* const* d_in, const int* in_sizes, int n_in,
                              void* d_out, int out_size, void* d_ws, size_t ws_size,
                              hipStream_t stream) {
  const float* x    = (const float*)d_in[0];
  const float* in_g = (const float*)d_in[1];
  const float* in_b = (const float*)d_in[2];
  const float* in_m = (const float*)d_in[3];
  const float* in_v = (const float*)d_in[4];
  const float* gW1  = (const float*)d_in[5];
  const float* gb1  = (const float*)d_in[6];
  const float* g_g  = (const float*)d_in[7];
  const float* g_b  = (const float*)d_in[8];
  const float* g_m  = (const float*)d_in[9];
  const float* g_v  = (const float*)d_in[10];
  const float* gW2  = (const float*)d_in[11];
  const float* gb2  = (const float*)d_in[12];
  const float* eW0  = (const float*)d_in[13];
  const float* eb0  = (const float*)d_in[14];
  const float* e0g  = (const float*)d_in[15];
  const float* e0b  = (const float*)d_in[16];
  const float* e0m  = (const float*)d_in[17];
  const float* e0v  = (const float*)d_in[18];
  const float* eW1  = (const float*)d_in[19];
  const float* eb1  = (const float*)d_in[20];
  const float* e1g  = (const float*)d_in[21];
  const float* e1b  = (const float*)d_in[22];
  const float* e1m  = (const float*)d_in[23];
  const float* e1v  = (const float*)d_in[24];
  const float* eW2  = (const float*)d_in[25];
  const float* eb2  = (const float*)d_in[26];
  const float* e2g  = (const float*)d_in[27];
  const float* e2b  = (const float*)d_in[28];
  const float* e2m  = (const float*)d_in[29];
  const float* e2v  = (const float*)d_in[30];
  const float* oW   = (const float*)d_in[31];
  const float* ob   = (const float*)d_in[32];
  float* out = (float*)d_out;
  const int Btot = in_sizes[0] / D;

  if (ws_size >= WS_BYTES && (Btot % TBR) == 0) {
    u16* ws = (u16*)d_ws;
    repack_w<<<TP_TOTAL / 4, 256, 0, stream>>>(eW0, eW1, eW2, gW1, gW2, ws);
    moe_mfma<<<Btot / TBR, NT, 0, stream>>>(
        x, in_g, in_b, in_m, in_v,
        gb1, g_g, g_b, g_m, g_v, gb2,
        eb0, e0g, e0b, e0m, e0v,
        eb1, e1g, e1b, e1m, e1v,
        eb2, e2g, e2b, e2m, e2v,
        oW, ob, ws, out);
  } else {
    moe_fused_fp32<<<Btot / 16, 256, 0, stream>>>(
        x, in_g, in_b, in_m, in_v,
        gW1, gb1, g_g, g_b, g_m, g_v, gW2, gb2,
        eW0, eb0, e0g, e0b, e0m, e0v,
        eW1, eb1, e1g, e1b, e1m, e1v,
        eW2, eb2, e2g, e2b, e2m, e2v,
        oW, ob, out);
  }
}

// Round 14
// 258.433 us; speedup vs baseline: 1.3557x; 1.2440x over previous
//
#include <hip/hip_runtime.h>
#include <hip/hip_bf16.h>

#define D   256
#define NE  8
#define G   128
#define H0  256
#define H1  128
#define H2  64
#define TBR 128
#define NT  512
#define EPS 1e-5f

typedef unsigned short u16;
typedef __attribute__((ext_vector_type(8))) short bf16x8;
typedef __attribute__((ext_vector_type(4))) float f32x4;
typedef __attribute__((ext_vector_type(4))) unsigned short u16x4;

#define MFMA16(a,b,c) __builtin_amdgcn_mfma_f32_16x16x32_bf16((a),(b),(c),0,0,0)

// ws layout: tile-pairs of 1024 u16 (512 hi + 512 lo), wave-fragment order:
// lane l holds B[k = kt*32 + 8*(l>>4) + j][n = nt*16 + (l&15)], j=0..7.
// EXPERT + gW1 tiles: hi = RNE-rounded bf16 (1-term consumption, lo unused).
// gW2 tiles: hi = truncated, lo = remainder (2-term consumption).
#define TP_EW0 1024   // 8e * 16nt * 8kt
#define TP_EW1 512    // 8e * 8nt * 8kt
#define TP_EW2 128    // 8e * 4nt * 4kt
#define TP_GW1 64     // 8nt * 8kt
#define TP_GW2 4      // 1nt(padded 16 cols) * 4kt
#define TPO_EW1 (TP_EW0)
#define TPO_EW2 (TP_EW0 + TP_EW1)
#define TPO_GW1 (TP_EW0 + TP_EW1 + TP_EW2)
#define TPO_GW2 (TPO_GW1 + TP_GW1)
#define TP_TOTAL (TPO_GW2 + TP_GW2)
#define WS_BYTES ((size_t)TP_TOTAL * 2048)

__device__ __forceinline__ u16 rne_bf16(float v) {
  unsigned u = __float_as_uint(v);
  u += 0x7FFFu + ((u >> 16) & 1u);
  return (u16)(u >> 16);
}

// ---------------------------------------------------------------- repack ----
__global__ __launch_bounds__(256) void repack_w(
    const float* __restrict__ eW0, const float* __restrict__ eW1,
    const float* __restrict__ eW2, const float* __restrict__ gW1,
    const float* __restrict__ gW2, u16* __restrict__ ws)
{
  const int wid = (blockIdx.x * 256 + threadIdx.x) >> 6;
  const int l   = threadIdx.x & 63;
  if (wid >= TP_TOTAL) return;
  const float* src; int ncols, nt, kt; bool pad8 = false;
  const bool one_term = (wid < TPO_GW2);   // experts + gW1: 1-term RNE
  if (wid < TP_EW0) {
    int e = wid >> 7, r = wid & 127; nt = r >> 3; kt = r & 7;
    src = eW0 + (size_t)e * D * H0; ncols = H0;
  } else if (wid < TPO_EW2) {
    int w2 = wid - TPO_EW1; int e = w2 >> 6, r = w2 & 63; nt = r >> 3; kt = r & 7;
    src = eW1 + (size_t)e * H0 * H1; ncols = H1;
  } else if (wid < TPO_GW1) {
    int w3 = wid - TPO_EW2; int e = w3 >> 4, r = w3 & 15; nt = r >> 2; kt = r & 3;
    src = eW2 + (size_t)e * H1 * H2; ncols = H2;
  } else if (wid < TPO_GW2) {
    int w4 = wid - TPO_GW1; nt = w4 >> 3; kt = w4 & 7;
    src = gW1; ncols = G;
  } else {
    kt = wid - TPO_GW2; nt = 0;
    src = gW2; ncols = NE; pad8 = true;   // pad cols 8..15 with zeros
  }
  const int n  = nt * 16 + (l & 15);
  const int k0 = kt * 32 + 8 * (l >> 4);
  u16 hi[8], lo[8];
  #pragma unroll
  for (int j = 0; j < 8; ++j) {
    float v = (pad8 && (l & 15) >= 8) ? 0.f : src[(size_t)(k0 + j) * ncols + (pad8 ? (n & 7) : n)];
    if (one_term) {
      hi[j] = rne_bf16(v);    // 1-term: round-to-nearest
      lo[j] = 0;
    } else {
      unsigned u = __float_as_uint(v);
      hi[j] = (u16)(u >> 16);
      float hf = __uint_as_float(u & 0xFFFF0000u);
      lo[j] = (u16)(__float_as_uint(v - hf) >> 16);
    }
  }
  u16* dst = ws + (size_t)wid * 1024 + l * 8;
  *(u16x4*)(dst + 0)       = u16x4{hi[0], hi[1], hi[2], hi[3]};
  *(u16x4*)(dst + 4)       = u16x4{hi[4], hi[5], hi[6], hi[7]};
  *(u16x4*)(dst + 512 + 0) = u16x4{lo[0], lo[1], lo[2], lo[3]};
  *(u16x4*)(dst + 512 + 4) = u16x4{lo[4], lo[5], lo[6], lo[7]};
}

// ------------------------------------------------------------- main MFMA ----
struct Smem {
  u16 xnh[TBR * D];   // 64 KiB, persistent
  u16 h0h[TBR * H0];  // 64 KiB (gating hidden gh in cols 0..127 pre-experts)
  union {
    u16 h1h[TBR * H1];    // 32 KiB (experts)
    float ss[2][D];       // Phase A/B only
    float part[4][2][32]; // final reduction only
  } u;
};                        // total 163840 B = 160 KiB exactly -> 1 block/CU

__device__ __forceinline__ int swz512(int r, int c) {
  return (r * 512 + ((c * 2) ^ ((r & 7) << 4))) >> 1;   // u16 index, row stride 512B
}
__device__ __forceinline__ int swz256(int r, int c) {
  return (r * 256 + ((c * 2) ^ ((r & 7) << 4))) >> 1;   // u16 index, row stride 256B
}
__device__ __forceinline__ bf16x8 ldA(const u16* p, int idx) {
  return *(const bf16x8*)(p + idx);
}

// R8 structure (262 us, best of 12 rounds): TBR=128, 8 waves, 1 block/CU
// (LDS=160KiB structural), (NT,2) register budget. Post-R8 experiments:
// R9 (4x4 acc) spilled; R10 (2x4 grid) traded cheap ds_reads for L2-latency
// weight loads (-25%); R11/12 (two 4-wave blocks) quadrupled weight loads
// per row (-18%). Weight-load count per MFMA is the binding constraint;
// this mapping minimizes it. Only change vs R8: gW1 is 1-term RNE.
__global__ __launch_bounds__(NT, 2) void moe_mfma(
    const float* __restrict__ x,
    const float* __restrict__ in_g, const float* __restrict__ in_b,
    const float* __restrict__ in_m, const float* __restrict__ in_v,
    const float* __restrict__ gb1,
    const float* __restrict__ g_g, const float* __restrict__ g_b,
    const float* __restrict__ g_m, const float* __restrict__ g_v,
    const float* __restrict__ gb2,
    const float* __restrict__ eb0,
    const float* __restrict__ e0g, const float* __restrict__ e0b,
    const float* __restrict__ e0m, const float* __restrict__ e0v,
    const float* __restrict__ eb1,
    const float* __restrict__ e1g, const float* __restrict__ e1b,
    const float* __restrict__ e1m, const float* __restrict__ e1v,
    const float* __restrict__ eb2,
    const float* __restrict__ e2g, const float* __restrict__ e2b,
    const float* __restrict__ e2m, const float* __restrict__ e2v,
    const float* __restrict__ oW, const float* __restrict__ ob,
    const u16* __restrict__ ws, float* __restrict__ out)
{
  __shared__ Smem sm;
  const int t = threadIdx.x;
  const int l = t & 63;
  const int w = t >> 6;            // wave 0..7
  const int row0 = blockIdx.x * TBR;
  const int rA  = l & 15;
  const int kg8 = 8 * (l >> 4);
  const int lg4 = (l >> 4) * 4;
  const int wg  = w >> 1;          // L2 / gating m-group (m-tiles 2wg, 2wg+1)
  const int np  = w & 1;           // L2 n-pair

  // ---- Phase A: input-BN scale/shift -> LDS (u region, dead until experts)
  if (t < D) {
    float s = in_g[t] * rsqrtf(in_v[t] + EPS);
    sm.u.ss[0][t] = s;
    sm.u.ss[1][t] = in_b[t] - in_m[t] * s;
  }
  __syncthreads();

  // ---- Phase B: load x, BN, RNE bf16 -> xnh (swizzled); 2 passes of 64 rows
  #pragma unroll
  for (int pass = 0; pass < 2; ++pass) {
    const int row = (t >> 3) + pass * 64;
    #pragma unroll
    for (int j = 0; j < 8; ++j) {
      const int cb = ((t & 7) + j * 8) * 4;
      const float4 xv = *(const float4*)(x + (size_t)(row0 + row) * D + cb);
      u16 h4[4];
      #pragma unroll
      for (int q = 0; q < 4; ++q) {
        float val = fmaf(((const float*)&xv)[q], sm.u.ss[0][cb + q], sm.u.ss[1][cb + q]);
        h4[q] = rne_bf16(val);
      }
      *(u16x4*)(sm.xnh + swz512(row, cb)) = u16x4{h4[0], h4[1], h4[2], h4[3]};
    }
  }
  __syncthreads();

  // ---- Phase C: gating hidden gh = relu(bn(xn@gW1+gb1)) -> h0h cols 0..127
  // wave w -> n-tile w, all 8 m-tiles (1-term RNE gW1)
  {
    f32x4 acc[8] = {};
    #pragma unroll
    for (int kt = 0; kt < 8; ++kt) {
      const size_t tp = (size_t)TPO_GW1 + (size_t)w * 8 + kt;
      const bf16x8 wh = *((const bf16x8*)(ws + tp * 1024) + l);
      #pragma unroll
      for (int mh = 0; mh < 2; ++mh) {
        bf16x8 ah[4];
        #pragma unroll
        for (int mi = 0; mi < 4; ++mi)
          ah[mi] = ldA(sm.xnh, swz512((mh * 4 + mi) * 16 + rA, kt * 32 + kg8));
        #pragma unroll
        for (int mi = 0; mi < 4; ++mi)
          acc[mh * 4 + mi] = MFMA16(ah[mi], wh, acc[mh * 4 + mi]);
      }
    }
    const int c = w * 16 + rA;
    const float s  = g_g[c] * rsqrtf(g_v[c] + EPS);
    const float sh = fmaf(gb1[c] - g_m[c], s, g_b[c]);
    #pragma unroll
    for (int mt = 0; mt < 8; ++mt)
      #pragma unroll
      for (int r = 0; r < 4; ++r)
        sm.h0h[swz512(mt * 16 + lg4 + r, c)] =
            rne_bf16(fmaxf(fmaf(acc[mt][r], s, sh), 0.f));
  }
  __syncthreads();

  // ---- Phase D: gate logits via MFMA (padded gW2, 2-term), in-reg softmax
  // wave computes gates for m-tiles {2wg, 2wg+1} (matches its L2 rows)
  f32x4 gmine[2];  // gate[row=(2wg+mi)*16+lg4+r][expert=rA], rA<8 valid
  #pragma unroll
  for (int mi = 0; mi < 2; ++mi) {
    f32x4 acc = {};
    #pragma unroll
    for (int kt = 0; kt < 4; ++kt) {
      const bf16x8 ah = ldA(sm.h0h, swz512((2 * wg + mi) * 16 + rA, kt * 32 + kg8));
      const size_t tp = (size_t)TPO_GW2 + kt;
      const bf16x8 wh = *((const bf16x8*)(ws + tp * 1024) + l);
      const bf16x8 wl = *((const bf16x8*)(ws + tp * 1024 + 512) + l);
      acc = MFMA16(ah, wh, acc);
      acc = MFMA16(ah, wl, acc);
    }
    #pragma unroll
    for (int r = 0; r < 4; ++r) {
      float v = (rA < 8) ? (acc[r] + gb2[rA]) : -3.4e38f;
      float mx = v;
      mx = fmaxf(mx, __shfl_xor(mx, 1));
      mx = fmaxf(mx, __shfl_xor(mx, 2));
      mx = fmaxf(mx, __shfl_xor(mx, 4));
      mx = fmaxf(mx, __shfl_xor(mx, 8));
      float p = expf(v - mx);          // -inf lanes -> 0
      float ssum = p;
      ssum += __shfl_xor(ssum, 1);
      ssum += __shfl_xor(ssum, 2);
      ssum += __shfl_xor(ssum, 4);
      ssum += __shfl_xor(ssum, 8);
      gmine[mi][r] = p / ssum;
    }
  }
  __syncthreads();

  // ---- Phase E: experts (2 barriers per expert); 1-term RNE weights
  f32x4 comb[2][2] = {};   // [mi][nti]
  for (int e = 0; e < NE; ++e) {
    // L0: h0 = relu(bn(xn @ eW0[e] + eb0)); wave w -> n-tiles {2w, 2w+1},
    // all 8 m-tiles
    #pragma unroll
    for (int nti = 0; nti < 2; ++nti) {
      f32x4 acc[8] = {};
      #pragma unroll
      for (int kt = 0; kt < 8; ++kt) {
        const size_t tp = ((size_t)e * 16 + 2 * w + nti) * 8 + kt;
        const bf16x8 wh = *((const bf16x8*)(ws + tp * 1024) + l);
        #pragma unroll
        for (int mh = 0; mh < 2; ++mh) {
          bf16x8 ah[4];
          #pragma unroll
          for (int mi = 0; mi < 4; ++mi)
            ah[mi] = ldA(sm.xnh, swz512((mh * 4 + mi) * 16 + rA, kt * 32 + kg8));
          #pragma unroll
          for (int mi = 0; mi < 4; ++mi)
            acc[mh * 4 + mi] = MFMA16(ah[mi], wh, acc[mh * 4 + mi]);
        }
      }
      const int c = (2 * w + nti) * 16 + rA;
      const float s  = e0g[e * H0 + c] * rsqrtf(e0v[e * H0 + c] + EPS);
      const float sh = fmaf(eb0[e * H0 + c] - e0m[e * H0 + c], s, e0b[e * H0 + c]);
      #pragma unroll
      for (int mt = 0; mt < 8; ++mt)
        #pragma unroll
        for (int r = 0; r < 4; ++r)
          sm.h0h[swz512(mt * 16 + lg4 + r, c)] =
              rne_bf16(fmaxf(fmaf(acc[mt][r], s, sh), 0.f));
    }
    __syncthreads();
    // L1: h1 = relu(bn(h0 @ eW1[e] + eb1)); wave w -> n-tile w, 8 m-tiles
    {
      f32x4 acc[8] = {};
      #pragma unroll
      for (int kt = 0; kt < 8; ++kt) {
        const size_t tp = TPO_EW1 + ((size_t)e * 8 + w) * 8 + kt;
        const bf16x8 wh = *((const bf16x8*)(ws + tp * 1024) + l);
        #pragma unroll
        for (int mh = 0; mh < 2; ++mh) {
          bf16x8 ah[4];
          #pragma unroll
          for (int mi = 0; mi < 4; ++mi)
            ah[mi] = ldA(sm.h0h, swz512((mh * 4 + mi) * 16 + rA, kt * 32 + kg8));
          #pragma unroll
          for (int mi = 0; mi < 4; ++mi)
            acc[mh * 4 + mi] = MFMA16(ah[mi], wh, acc[mh * 4 + mi]);
        }
      }
      const int c = w * 16 + rA;
      const float s  = e1g[e * H1 + c] * rsqrtf(e1v[e * H1 + c] + EPS);
      const float sh = fmaf(eb1[e * H1 + c] - e1m[e * H1 + c], s, e1b[e * H1 + c]);
      #pragma unroll
      for (int mt = 0; mt < 8; ++mt)
        #pragma unroll
        for (int r = 0; r < 4; ++r)
          sm.u.h1h[swz256(mt * 16 + lg4 + r, c)] =
              rne_bf16(fmaxf(fmaf(acc[mt][r], s, sh), 0.f));
    }
    __syncthreads();
    // L2 + gated combine (h2 stays in registers);
    // wave -> m-tiles {2wg, 2wg+1}, n-tiles {2np, 2np+1}
    #pragma unroll
    for (int nti = 0; nti < 2; ++nti) {
      f32x4 acc2[2] = {};
      #pragma unroll
      for (int kt = 0; kt < 4; ++kt) {
        const size_t tp = TPO_EW2 + ((size_t)e * 4 + 2 * np + nti) * 4 + kt;
        const bf16x8 wh = *((const bf16x8*)(ws + tp * 1024) + l);
        #pragma unroll
        for (int mi = 0; mi < 2; ++mi) {
          const bf16x8 ah = ldA(sm.u.h1h, swz256((2 * wg + mi) * 16 + rA, kt * 32 + kg8));
          acc2[mi] = MFMA16(ah, wh, acc2[mi]);
        }
      }
      const int c = (2 * np + nti) * 16 + rA;
      const float s  = e2g[e * H2 + c] * rsqrtf(e2v[e * H2 + c] + EPS);
      const float sh = fmaf(eb2[e * H2 + c] - e2m[e * H2 + c], s, e2b[e * H2 + c]);
      #pragma unroll
      for (int mi = 0; mi < 2; ++mi)
        #pragma unroll
        for (int r = 0; r < 4; ++r) {
          const float gt = __shfl(gmine[mi][r], (l & 48) | e);  // gate[row][e]
          comb[mi][nti][r] = fmaf(gt, fmaxf(fmaf(acc2[mi][r], s, sh), 0.f),
                                  comb[mi][nti][r]);
        }
    }
    // hazard-free: h0h rewritten only after post-L1 barrier of this expert;
    // h1h rewritten only after post-L0 barrier of next expert.
  }

  // ---- Phase F: out = comb @ oW + ob (part aliases h1h -> barrier first)
  const float w0 = oW[(2 * np + 0) * 16 + rA];
  const float w1 = oW[(2 * np + 1) * 16 + rA];
  __syncthreads();
  #pragma unroll
  for (int mi = 0; mi < 2; ++mi)
    #pragma unroll
    for (int r = 0; r < 4; ++r) {
      float sx = comb[mi][0][r] * w0 + comb[mi][1][r] * w1;
      sx += __shfl_xor(sx, 1);
      sx += __shfl_xor(sx, 2);
      sx += __shfl_xor(sx, 4);
      sx += __shfl_xor(sx, 8);
      if (rA == 0) sm.u.part[wg][np][mi * 16 + lg4 + r] = sx;
    }
  __syncthreads();
  if (t < TBR)
    out[row0 + t] = sm.u.part[t >> 5][0][t & 31] +
                    sm.u.part[t >> 5][1][t & 31] + ob[0];
}

// ------------------------------------------------- fp32 fallback (verified) -
struct SmemF {
  float xn[16][D]; float h0[16][H0]; float h1[16][H1]; float gates[16][NE];
};
__global__ __launch_bounds__(256, 2) void moe_fused_fp32(
    const float* __restrict__ x,
    const float* __restrict__ in_g, const float* __restrict__ in_b,
    const float* __restrict__ in_m, const float* __restrict__ in_v,
    const float* __restrict__ gW1, const float* __restrict__ gb1,
    const float* __restrict__ g_g, const float* __restrict__ g_b,
    const float* __restrict__ g_m, const float* __restrict__ g_v,
    const float* __restrict__ gW2, const float* __restrict__ gb2,
    const float* __restrict__ eW0, const float* __restrict__ eb0,
    const float* __restrict__ e0g, const float* __restrict__ e0b,
    const float* __restrict__ e0m, const float* __restrict__ e0v,
    const float* __restrict__ eW1, const float* __restrict__ eb1,
    const float* __restrict__ e1g, const float* __restrict__ e1b,
    const float* __restrict__ e1m, const float* __restrict__ e1v,
    const float* __restrict__ eW2, const float* __restrict__ eb2,
    const float* __restrict__ e2g, const float* __restrict__ e2b,
    const float* __restrict__ e2m, const float* __restrict__ e2v,
    const float* __restrict__ oW, const float* __restrict__ ob,
    float* __restrict__ out)
{
  __shared__ SmemF sm;
  const int t = threadIdx.x;
  const int row0 = blockIdx.x * 16;
  {
    const int c = t;
    const float s  = in_g[c] * rsqrtf(in_v[c] + EPS);
    const float sh = in_b[c] - in_m[c] * s;
    #pragma unroll
    for (int r = 0; r < 16; ++r)
      sm.xn[r][c] = fmaf(x[(size_t)(row0 + r) * D + c], s, sh);
  }
  __syncthreads();
  {
    const int rg = t >> 6, c0 = (t & 63) * 2;
    float acc[4][2] = {};
    for (int k = 0; k < D; k += 4) {
      float4 xa[4];
      #pragma unroll
      for (int r = 0; r < 4; ++r) xa[r] = *(const float4*)(&sm.xn[rg * 4 + r][k]);
      float2 wv[4];
      #pragma unroll
      for (int kk = 0; kk < 4; ++kk) wv[kk] = *(const float2*)(&gW1[(size_t)(k + kk) * G + c0]);
      #pragma unroll
      for (int r = 0; r < 4; ++r) {
        const float* xv = (const float*)&xa[r];
        #pragma unroll
        for (int kk = 0; kk < 4; ++kk) {
          acc[r][0] = fmaf(xv[kk], wv[kk].x, acc[r][0]);
          acc[r][1] = fmaf(xv[kk], wv[kk].y, acc[r][1]);
        }
      }
    }
    #pragma unroll
    for (int j = 0; j < 2; ++j) {
      const int c = c0 + j;
      const float s  = g_g[c] * rsqrtf(g_v[c] + EPS);
      const float sh = fmaf(gb1[c] - g_m[c], s, g_b[c]);
      #pragma unroll
      for (int r = 0; r < 4; ++r)
        sm.h1[rg * 4 + r][c] = fmaxf(fmaf(acc[r][j], s, sh), 0.f);
    }
  }
  __syncthreads();
  if (t < 16 * NE) {
    const int r = t >> 3, e = t & 7;
    float acc = gb2[e];
    for (int k = 0; k < G; k += 4) {
      const float4 hv = *(const float4*)(&sm.h1[r][k]);
      acc = fmaf(hv.x, gW2[(k + 0) * NE + e], acc);
      acc = fmaf(hv.y, gW2[(k + 1) * NE + e], acc);
      acc = fmaf(hv.z, gW2[(k + 2) * NE + e], acc);
      acc = fmaf(hv.w, gW2[(k + 3) * NE + e], acc);
    }
    sm.gates[r][e] = acc;
  }
  __syncthreads();
  if (t < 16) {
    float v[NE]; float mx = -3.4e38f;
    #pragma unroll
    for (int e = 0; e < NE; ++e) { v[e] = sm.gates[t][e]; mx = fmaxf(mx, v[e]); }
    float ssum = 0.f;
    #pragma unroll
    for (int e = 0; e < NE; ++e) { v[e] = expf(v[e] - mx); ssum += v[e]; }
    const float inv = 1.f / ssum;
    #pragma unroll
    for (int e = 0; e < NE; ++e) sm.gates[t][e] = v[e] * inv;
  }
  __syncthreads();
  float comb[4] = {0.f, 0.f, 0.f, 0.f};
  const int rgA = t >> 6, c0A = (t & 63) * 4;
  const int rg1 = t >> 5, c01 = (t & 31) * 4;
  const int r2  = t >> 4, c02 = (t & 15) * 4;
  for (int e = 0; e < NE; ++e) {
    {
      const float* __restrict__ W = eW0 + (size_t)e * D * H0;
      float acc[4][4] = {};
      for (int k = 0; k < D; k += 4) {
        float4 xa[4];
        #pragma unroll
        for (int r = 0; r < 4; ++r) xa[r] = *(const float4*)(&sm.xn[rgA * 4 + r][k]);
        float4 wv[4];
        #pragma unroll
        for (int kk = 0; kk < 4; ++kk) wv[kk] = *(const float4*)(&W[(size_t)(k + kk) * H0 + c0A]);
        #pragma unroll
        for (int r = 0; r < 4; ++r) {
          const float* xv = (const float*)&xa[r];
          #pragma unroll
          for (int kk = 0; kk < 4; ++kk) {
            acc[r][0] = fmaf(xv[kk], wv[kk].x, acc[r][0]);
            acc[r][1] = fmaf(xv[kk], wv[kk].y, acc[r][1]);
            acc[r][2] = fmaf(xv[kk], wv[kk].z, acc[r][2]);
            acc[r][3] = fmaf(xv[kk], wv[kk].w, acc[r][3]);
          }
        }
      }
      const float4 gg = *(const float4*)(&e0g[e * H0 + c0A]);
      const float4 bb = *(const float4*)(&e0b[e * H0 + c0A]);
      const float4 mm = *(const float4*)(&e0m[e * H0 + c0A]);
      const float4 vv = *(const float4*)(&e0v[e * H0 + c0A]);
      const float4 bi = *(const float4*)(&eb0[e * H0 + c0A]);
      float s[4], sh[4];
      s[0] = gg.x * rsqrtf(vv.x + EPS); sh[0] = fmaf(bi.x - mm.x, s[0], bb.x);
      s[1] = gg.y * rsqrtf(vv.y + EPS); sh[1] = fmaf(bi.y - mm.y, s[1], bb.y);
      s[2] = gg.z * rsqrtf(vv.z + EPS); sh[2] = fmaf(bi.z - mm.z, s[2], bb.z);
      s[3] = gg.w * rsqrtf(vv.w + EPS); sh[3] = fmaf(bi.w - mm.w, s[3], bb.w);
      #pragma unroll
      for (int r = 0; r < 4; ++r) {
        float4 o;
        o.x = fmaxf(fmaf(acc[r][0], s[0], sh[0]), 0.f);
        o.y = fmaxf(fmaf(acc[r][1], s[1], sh[1]), 0.f);
        o.z = fmaxf(fmaf(acc[r][2], s[2], sh[2]), 0.f);
        o.w = fmaxf(fmaf(acc[r][3], s[3], sh[3]), 0.f);
        *(float4*)(&sm.h0[rgA * 4 + r][c0A]) = o;
      }
    }
    __syncthreads();
    {
      const float* __restrict__ W = eW1 + (size_t)e * H0 * H1;
      float acc[2][4] = {};
      for (int k = 0; k < H0; k += 4) {
        float4 xa[2];
        #pragma unroll
        for (int r = 0; r < 2; ++r) xa[r] = *(const float4*)(&sm.h0[rg1 * 2 + r][k]);
        float4 wv[4];
        #pragma unroll
        for (int kk = 0; kk < 4; ++kk) wv[kk] = *(const float4*)(&W[(size_t)(k + kk) * H1 + c01]);
        #pragma unroll
        for (int r = 0; r < 2; ++r) {
          const float* xv = (const float*)&xa[r];
          #pragma unroll
          for (int kk = 0; kk < 4; ++kk) {
            acc[r][0] = fmaf(xv[kk], wv[kk].x, acc[r][0]);
            acc[r][1] = fmaf(xv[kk], wv[kk].y, acc[r][1]);
            acc[r][2] = fmaf(xv[kk], wv[kk].z, acc[r][2]);
            acc[r][3] = fmaf(xv[kk], wv[kk].w, acc[r][3]);
          }
        }
      }
      const float4 gg = *(const float4*)(&e1g[e * H1 + c01]);
      const float4 bb = *(const float4*)(&e1b[e * H1 + c01]);
      const float4 mm = *(const float4*)(&e1m[e * H1 + c01]);
      const float4 vv = *(const float4*)(&e1v[e * H1 + c01]);
      const float4 bi = *(const float4*)(&eb1[e * H1 + c01]);
      float s[4], sh[4];
      s[0] = gg.x * rsqrtf(vv.x + EPS); sh[0] = fmaf(bi.x - mm.x, s[0], bb.x);
      s[1] = gg.y * rsqrtf(vv.y + EPS); sh[1] = fmaf(bi.y - mm.y, s[1], bb.y);
      s[2] = gg.z * rsqrtf(vv.z + EPS); sh[2] = fmaf(bi.z - mm.z, s[2], bb.z);
      s[3] = gg.w * rsqrtf(vv.w + EPS); sh[3] = fmaf(bi.w - mm.w, s[3], bb.w);
      #pragma unroll
      for (int r = 0; r < 2; ++r) {
        float4 o;
        o.x = fmaxf(fmaf(acc[r][0], s[0], sh[0]), 0.f);
        o.y = fmaxf(fmaf(acc[r][1], s[1], sh[1]), 0.f);
        o.z = fmaxf(fmaf(acc[r][2], s[2], sh[2]), 0.f);
        o.w = fmaxf(fmaf(acc[r][3], s[3], sh[3]), 0.f);
        *(float4*)(&sm.h1[rg1 * 2 + r][c01]) = o;
      }
    }
    __syncthreads();
    {
      const float* __restrict__ W = eW2 + (size_t)e * H1 * H2;
      float acc[4] = {};
      for (int k = 0; k < H1; k += 4) {
        const float4 xa = *(const float4*)(&sm.h1[r2][k]);
        const float4 w0 = *(const float4*)(&W[(size_t)(k + 0) * H2 + c02]);
        const float4 w1 = *(const float4*)(&W[(size_t)(k + 1) * H2 + c02]);
        const float4 w2 = *(const float4*)(&W[(size_t)(k + 2) * H2 + c02]);
        const float4 w3 = *(const float4*)(&W[(size_t)(k + 3) * H2 + c02]);
        acc[0] = fmaf(xa.x, w0.x, acc[0]); acc[1] = fmaf(xa.x, w0.y, acc[1]);
        acc[2] = fmaf(xa.x, w0.z, acc[2]); acc[3] = fmaf(xa.x, w0.w, acc[3]);
        acc[0] = fmaf(xa.y, w1.x, acc[0]); acc[1] = fmaf(xa.y, w1.y, acc[1]);
        acc[2] = fmaf(xa.y, w1.z, acc[2]); acc[3] = fmaf(xa.y, w1.w, acc[3]);
        acc[0] = fmaf(xa.z, w2.x, acc[0]); acc[1] = fmaf(xa.z, w2.y, acc[1]);
        acc[2] = fmaf(xa.z, w2.z, acc[2]); acc[3] = fmaf(xa.z, w2.w, acc[3]);
        acc[0] = fmaf(xa.w, w3.x, acc[0]); acc[1] = fmaf(xa.w, w3.y, acc[1]);
        acc[2] = fmaf(xa.w, w3.z, acc[2]); acc[3] = fmaf(xa.w, w3.w, acc[3]);
      }
      const float4 gg = *(const float4*)(&e2g[e * H2 + c02]);
      const float4 bb = *(const float4*)(&e2b[e * H2 + c02]);
      const float4 mm = *(const float4*)(&e2m[e * H2 + c02]);
      const float4 vv = *(const float4*)(&e2v[e * H2 + c02]);
      const float4 bi = *(const float4*)(&eb2[e * H2 + c02]);
      float s[4], sh[4];
      s[0] = gg.x * rsqrtf(vv.x + EPS); sh[0] = fmaf(bi.x - mm.x, s[0], bb.x);
      s[1] = gg.y * rsqrtf(vv.y + EPS); sh[1] = fmaf(bi.y - mm.y, s[1], bb.y);
      s[2] = gg.z * rsqrtf(vv.z + EPS); sh[2] = fmaf(bi.z - mm.z, s[2], bb.z);
      s[3] = gg.w * rsqrtf(vv.w + EPS); sh[3] = fmaf(bi.w - mm.w, s[3], bb.w);
      const float gate = sm.gates[r2][e];
      comb[0] = fmaf(gate, fmaxf(fmaf(acc[0], s[0], sh[0]), 0.f), comb[0]);
      comb[1] = fmaf(gate, fmaxf(fmaf(acc[1], s[1], sh[1]), 0.f), comb[1]);
      comb[2] = fmaf(gate, fmaxf(fmaf(acc[2], s[2], sh[2]), 0.f), comb[2]);
      comb[3] = fmaf(gate, fmaxf(fmaf(acc[3], s[3], sh[3]), 0.f), comb[3]);
    }
  }
  float part = comb[0] * oW[c02 + 0] + comb[1] * oW[c02 + 1] +
               comb[2] * oW[c02 + 2] + comb[3] * oW[c02 + 3];
  part += __shfl_xor(part, 1);
  part += __shfl_xor(part, 2);
  part += __shfl_xor(part, 4);
  part += __shfl_xor(part, 8);
  if ((t & 15) == 0) out[row0 + r2] = part + ob[0];
}

// ------------------------------------------------------------------ launch --
extern "C" void kernel_launch(void* const* d_in, const int* in_sizes, int n_in,
                              void* d_out, int out_size, void* d_ws, size_t ws_size,
                              hipStream_t stream) {
  const float* x    = (const float*)d_in[0];
  const float* in_g = (const float*)d_in[1];
  const float* in_b = (const float*)d_in[2];
  const float* in_m = (const float*)d_in[3];
  const float* in_v = (const float*)d_in[4];
  const float* gW1  = (const float*)d_in[5];
  const float* gb1  = (const float*)d_in[6];
  const float* g_g  = (const float*)d_in[7];
  const float* g_b  = (const float*)d_in[8];
  const float* g_m  = (const float*)d_in[9];
  const float* g_v  = (const float*)d_in[10];
  const float* gW2  = (const float*)d_in[11];
  const float* gb2  = (const float*)d_in[12];
  const float* eW0  = (const float*)d_in[13];
  const float* eb0  = (const float*)d_in[14];
  const float* e0g  = (const float*)d_in[15];
  const float* e0b  = (const float*)d_in[16];
  const float* e0m  = (const float*)d_in[17];
  const float* e0v  = (const float*)d_in[18];
  const float* eW1  = (const float*)d_in[19];
  const float* eb1  = (const float*)d_in[20];
  const float* e1g  = (const float*)d_in[21];
  const float* e1b  = (const float*)d_in[22];
  const float* e1m  = (const float*)d_in[23];
  const float* e1v  = (const float*)d_in[24];
  const float* eW2  = (const float*)d_in[25];
  const float* eb2  = (const float*)d_in[26];
  const float* e2g  = (const float*)d_in[27];
  const float* e2b  = (const float*)d_in[28];
  const float* e2m  = (const float*)d_in[29];
  const float* e2v  = (const float*)d_in[30];
  const float* oW   = (const float*)d_in[31];
  const float* ob   = (const float*)d_in[32];
  float* out = (float*)d_out;
  const int Btot = in_sizes[0] / D;

  if (ws_size >= WS_BYTES && (Btot % TBR) == 0) {
    u16* ws = (u16*)d_ws;
    repack_w<<<TP_TOTAL / 4, 256, 0, stream>>>(eW0, eW1, eW2, gW1, gW2, ws);
    moe_mfma<<<Btot / TBR, NT, 0, stream>>>(
        x, in_g, in_b, in_m, in_v,
        gb1, g_g, g_b, g_m, g_v, gb2,
        eb0, e0g, e0b, e0m, e0v,
        eb1, e1g, e1b, e1m, e1v,
        eb2, e2g, e2b, e2m, e2v,
        oW, ob, ws, out);
  } else {
    moe_fused_fp32<<<Btot / 16, 256, 0, stream>>>(
        x, in_g, in_b, in_m, in_v,
        gW1, gb1, g_g, g_b, g_m, g_v, gW2, gb2,
        eW0, eb0, e0g, e0b, e0m, e0v,
        eW1, eb1, e1g, e1b, e1m, e1v,
        eW2, eb2, e2g, e2b, e2m, e2v,
        oW, ob, out);
  }
}

// Round 15
// 201.017 us; speedup vs baseline: 1.7429x; 1.2856x over previous
//
#include <hip/hip_runtime.h>
#include <hip/hip_bf16.h>

#define D   256
#define NE  8
#define G   128
#define H0  256
#define H1  128
#define H2  64
#define TBR 128
#define NT  512
#define EPS 1e-5f

typedef unsigned short u16;
typedef __attribute__((ext_vector_type(8))) short bf16x8;
typedef __attribute__((ext_vector_type(4))) float f32x4;
typedef __attribute__((ext_vector_type(16))) float f32x16;
typedef __attribute__((ext_vector_type(4))) unsigned short u16x4;

#define MFMA16(a,b,c) __builtin_amdgcn_mfma_f32_16x16x32_bf16((a),(b),(c),0,0,0)
#define MFMA32(a,b,c) __builtin_amdgcn_mfma_f32_32x32x16_bf16((a),(b),(c),0,0,0)

// ws layout: tile-pairs of 1024 u16 (512 hi + 512 lo).
// EW0/EW1 are 32x32x16 B-frags: lane l holds B[k=kt*16+8*(l>>5)+j][n=nt*32+(l&31)].
// EW2/GW1/GW2 are 16x16x32 B-frags: lane l holds B[k=kt*32+8*(l>>4)+j][n=nt*16+(l&15)].
// Experts + gW1: hi = RNE bf16 (1-term). gW2: hi=trunc, lo=remainder (2-term).
#define TP_EW0 1024   // 8e * 8nt(32) * 16kt
#define TP_EW1 512    // 8e * 4nt(32) * 16kt
#define TP_EW2 128    // 8e * 4nt * 4kt
#define TP_GW1 64     // 8nt * 8kt
#define TP_GW2 4      // 1nt(padded 16 cols) * 4kt
#define TPO_EW1 (TP_EW0)
#define TPO_EW2 (TP_EW0 + TP_EW1)
#define TPO_GW1 (TP_EW0 + TP_EW1 + TP_EW2)
#define TPO_GW2 (TPO_GW1 + TP_GW1)
#define TP_TOTAL (TPO_GW2 + TP_GW2)
#define WS_BYTES ((size_t)TP_TOTAL * 2048)

__device__ __forceinline__ u16 rne_bf16(float v) {
  unsigned u = __float_as_uint(v);
  u += 0x7FFFu + ((u >> 16) & 1u);
  return (u16)(u >> 16);
}

// ---------------------------------------------------------------- repack ----
__global__ __launch_bounds__(256) void repack_w(
    const float* __restrict__ eW0, const float* __restrict__ eW1,
    const float* __restrict__ eW2, const float* __restrict__ gW1,
    const float* __restrict__ gW2, u16* __restrict__ ws)
{
  const int wid = (blockIdx.x * 256 + threadIdx.x) >> 6;
  const int l   = threadIdx.x & 63;
  if (wid >= TP_TOTAL) return;
  const float* src; int ncols, nt, kt; bool pad8 = false, tile32 = false;
  const bool one_term = (wid < TPO_GW2);   // experts + gW1: 1-term RNE
  if (wid < TP_EW0) {
    int e = wid >> 7, r = wid & 127; nt = r >> 4; kt = r & 15; tile32 = true;
    src = eW0 + (size_t)e * D * H0; ncols = H0;
  } else if (wid < TPO_EW2) {
    int w2 = wid - TPO_EW1; int e = w2 >> 6, r = w2 & 63; nt = r >> 4; kt = r & 15; tile32 = true;
    src = eW1 + (size_t)e * H0 * H1; ncols = H1;
  } else if (wid < TPO_GW1) {
    int w3 = wid - TPO_EW2; int e = w3 >> 4, r = w3 & 15; nt = r >> 2; kt = r & 3;
    src = eW2 + (size_t)e * H1 * H2; ncols = H2;
  } else if (wid < TPO_GW2) {
    int w4 = wid - TPO_GW1; nt = w4 >> 3; kt = w4 & 7;
    src = gW1; ncols = G;
  } else {
    kt = wid - TPO_GW2; nt = 0;
    src = gW2; ncols = NE; pad8 = true;   // pad cols 8..15 with zeros
  }
  const int n  = tile32 ? nt * 32 + (l & 31) : nt * 16 + (l & 15);
  const int k0 = tile32 ? kt * 16 + 8 * (l >> 5) : kt * 32 + 8 * (l >> 4);
  u16 hi[8], lo[8];
  #pragma unroll
  for (int j = 0; j < 8; ++j) {
    float v = (pad8 && (l & 15) >= 8) ? 0.f : src[(size_t)(k0 + j) * ncols + (pad8 ? (n & 7) : n)];
    if (one_term) {
      hi[j] = rne_bf16(v);    // 1-term: round-to-nearest
      lo[j] = 0;
    } else {
      unsigned u = __float_as_uint(v);
      hi[j] = (u16)(u >> 16);
      float hf = __uint_as_float(u & 0xFFFF0000u);
      lo[j] = (u16)(__float_as_uint(v - hf) >> 16);
    }
  }
  u16* dst = ws + (size_t)wid * 1024 + l * 8;
  *(u16x4*)(dst + 0)       = u16x4{hi[0], hi[1], hi[2], hi[3]};
  *(u16x4*)(dst + 4)       = u16x4{hi[4], hi[5], hi[6], hi[7]};
  *(u16x4*)(dst + 512 + 0) = u16x4{lo[0], lo[1], lo[2], lo[3]};
  *(u16x4*)(dst + 512 + 4) = u16x4{lo[4], lo[5], lo[6], lo[7]};
}

// ------------------------------------------------------------- main MFMA ----
struct Smem {
  u16 xnh[TBR * D];   // 64 KiB, persistent
  u16 h0h[TBR * H0];  // 64 KiB (gating hidden gh in cols 0..127 pre-experts)
  union {
    u16 h1h[TBR * H1];    // 32 KiB (experts)
    float ss[2][D];       // Phase A/B only
    float part[4][2][32]; // final reduction only
  } u;
};                        // total 163840 B = 160 KiB exactly -> 1 block/CU

// XOR (row&15)<<4: bijective (<= 240 < row stride), keeps 16B alignment.
// Widened from &7 so 32-lane row-spread reads (32x32 A-frags) are ~2-way.
__device__ __forceinline__ int swz512(int r, int c) {
  return (r * 512 + ((c * 2) ^ ((r & 15) << 4))) >> 1;  // u16 idx, stride 512B
}
__device__ __forceinline__ int swz256(int r, int c) {
  return (r * 256 + ((c * 2) ^ ((r & 15) << 4))) >> 1;  // u16 idx, stride 256B
}
__device__ __forceinline__ bf16x8 ldA(const u16* p, int idx) {
  return *(const bf16x8*)(p + idx);
}

// R13 structure (258 us best) + 32x32x16 MFMA for L0/L1: halves ds_read and
// MFMA instruction count at equal weight-load BYTES (+8 load instr in L1).
// Live-reg budget: L0 = 64 AGPR acc + ~50 VGPR < observed ~128 cap (R9's
// spill was 64 AGPR + 4 concurrent wh streams; here 1). Tripwire: WRITE_SIZE.
__global__ __launch_bounds__(NT, 2) void moe_mfma(
    const float* __restrict__ x,
    const float* __restrict__ in_g, const float* __restrict__ in_b,
    const float* __restrict__ in_m, const float* __restrict__ in_v,
    const float* __restrict__ gb1,
    const float* __restrict__ g_g, const float* __restrict__ g_b,
    const float* __restrict__ g_m, const float* __restrict__ g_v,
    const float* __restrict__ gb2,
    const float* __restrict__ eb0,
    const float* __restrict__ e0g, const float* __restrict__ e0b,
    const float* __restrict__ e0m, const float* __restrict__ e0v,
    const float* __restrict__ eb1,
    const float* __restrict__ e1g, const float* __restrict__ e1b,
    const float* __restrict__ e1m, const float* __restrict__ e1v,
    const float* __restrict__ eb2,
    const float* __restrict__ e2g, const float* __restrict__ e2b,
    const float* __restrict__ e2m, const float* __restrict__ e2v,
    const float* __restrict__ oW, const float* __restrict__ ob,
    const u16* __restrict__ ws, float* __restrict__ out)
{
  __shared__ Smem sm;
  const int t = threadIdx.x;
  const int l = t & 63;
  const int w = t >> 6;            // wave 0..7
  const int row0 = blockIdx.x * TBR;
  const int rA  = l & 15;          // 16x16 lane col
  const int kg8 = 8 * (l >> 4);    // 16x16 k sub-offset
  const int lg4 = (l >> 4) * 4;
  const int rB  = l & 31;          // 32x32 lane col
  const int kg8b = 8 * (l >> 5);   // 32x32 k sub-offset
  const int hb4 = 4 * (l >> 5);    // 32x32 C row base
  const int wg  = w >> 1;          // L2 / gating m-group (m-tiles 2wg, 2wg+1)
  const int np  = w & 1;           // L2 n-pair

  // ---- Phase A: input-BN scale/shift -> LDS (u region, dead until experts)
  if (t < D) {
    float s = in_g[t] * rsqrtf(in_v[t] + EPS);
    sm.u.ss[0][t] = s;
    sm.u.ss[1][t] = in_b[t] - in_m[t] * s;
  }
  __syncthreads();

  // ---- Phase B: load x, BN, RNE bf16 -> xnh (swizzled); 2 passes of 64 rows
  #pragma unroll
  for (int pass = 0; pass < 2; ++pass) {
    const int row = (t >> 3) + pass * 64;
    #pragma unroll
    for (int j = 0; j < 8; ++j) {
      const int cb = ((t & 7) + j * 8) * 4;
      const float4 xv = *(const float4*)(x + (size_t)(row0 + row) * D + cb);
      u16 h4[4];
      #pragma unroll
      for (int q = 0; q < 4; ++q) {
        float val = fmaf(((const float*)&xv)[q], sm.u.ss[0][cb + q], sm.u.ss[1][cb + q]);
        h4[q] = rne_bf16(val);
      }
      *(u16x4*)(sm.xnh + swz512(row, cb)) = u16x4{h4[0], h4[1], h4[2], h4[3]};
    }
  }
  __syncthreads();

  // ---- Phase C: gating hidden gh = relu(bn(xn@gW1+gb1)) -> h0h cols 0..127
  // 16x16 path: wave w -> n-tile w, all 8 m-tiles (1-term RNE gW1)
  {
    f32x4 acc[8] = {};
    #pragma unroll
    for (int kt = 0; kt < 8; ++kt) {
      const size_t tp = (size_t)TPO_GW1 + (size_t)w * 8 + kt;
      const bf16x8 wh = *((const bf16x8*)(ws + tp * 1024) + l);
      #pragma unroll
      for (int mh = 0; mh < 2; ++mh) {
        bf16x8 ah[4];
        #pragma unroll
        for (int mi = 0; mi < 4; ++mi)
          ah[mi] = ldA(sm.xnh, swz512((mh * 4 + mi) * 16 + rA, kt * 32 + kg8));
        #pragma unroll
        for (int mi = 0; mi < 4; ++mi)
          acc[mh * 4 + mi] = MFMA16(ah[mi], wh, acc[mh * 4 + mi]);
      }
    }
    const int c = w * 16 + rA;
    const float s  = g_g[c] * rsqrtf(g_v[c] + EPS);
    const float sh = fmaf(gb1[c] - g_m[c], s, g_b[c]);
    #pragma unroll
    for (int mt = 0; mt < 8; ++mt)
      #pragma unroll
      for (int r = 0; r < 4; ++r)
        sm.h0h[swz512(mt * 16 + lg4 + r, c)] =
            rne_bf16(fmaxf(fmaf(acc[mt][r], s, sh), 0.f));
  }
  __syncthreads();

  // ---- Phase D: gate logits via MFMA (padded gW2, 2-term), in-reg softmax
  f32x4 gmine[2];  // gate[row=(2wg+mi)*16+lg4+r][expert=rA], rA<8 valid
  #pragma unroll
  for (int mi = 0; mi < 2; ++mi) {
    f32x4 acc = {};
    #pragma unroll
    for (int kt = 0; kt < 4; ++kt) {
      const bf16x8 ah = ldA(sm.h0h, swz512((2 * wg + mi) * 16 + rA, kt * 32 + kg8));
      const size_t tp = (size_t)TPO_GW2 + kt;
      const bf16x8 wh = *((const bf16x8*)(ws + tp * 1024) + l);
      const bf16x8 wl = *((const bf16x8*)(ws + tp * 1024 + 512) + l);
      acc = MFMA16(ah, wh, acc);
      acc = MFMA16(ah, wl, acc);
    }
    #pragma unroll
    for (int r = 0; r < 4; ++r) {
      float v = (rA < 8) ? (acc[r] + gb2[rA]) : -3.4e38f;
      float mx = v;
      mx = fmaxf(mx, __shfl_xor(mx, 1));
      mx = fmaxf(mx, __shfl_xor(mx, 2));
      mx = fmaxf(mx, __shfl_xor(mx, 4));
      mx = fmaxf(mx, __shfl_xor(mx, 8));
      float p = expf(v - mx);          // -inf lanes -> 0
      float ssum = p;
      ssum += __shfl_xor(ssum, 1);
      ssum += __shfl_xor(ssum, 2);
      ssum += __shfl_xor(ssum, 4);
      ssum += __shfl_xor(ssum, 8);
      gmine[mi][r] = p / ssum;
    }
  }
  __syncthreads();

  // ---- Phase E: experts (2 barriers per expert); 1-term RNE weights
  f32x4 comb[2][2] = {};   // [mi][nti]
  for (int e = 0; e < NE; ++e) {
    // L0 (32x32): h0 = relu(bn(xn @ eW0[e] + eb0));
    // wave w -> n-tile w (32 cols), m-tiles 0..3 (32 rows each)
    {
      f32x16 acc[4] = {};
      #pragma unroll
      for (int kt = 0; kt < 16; ++kt) {
        const size_t tp = (size_t)e * 128 + (size_t)w * 16 + kt;
        const bf16x8 wh = *((const bf16x8*)(ws + tp * 1024) + l);
        bf16x8 ah[4];
        #pragma unroll
        for (int mi = 0; mi < 4; ++mi)
          ah[mi] = ldA(sm.xnh, swz512(mi * 32 + rB, kt * 16 + kg8b));
        #pragma unroll
        for (int mi = 0; mi < 4; ++mi)
          acc[mi] = MFMA32(ah[mi], wh, acc[mi]);
      }
      const int c = w * 32 + rB;
      const float s  = e0g[e * H0 + c] * rsqrtf(e0v[e * H0 + c] + EPS);
      const float sh = fmaf(eb0[e * H0 + c] - e0m[e * H0 + c], s, e0b[e * H0 + c]);
      #pragma unroll
      for (int mi = 0; mi < 4; ++mi)
        #pragma unroll
        for (int reg = 0; reg < 16; ++reg) {
          const int row = mi * 32 + (reg & 3) + 8 * (reg >> 2) + hb4;
          sm.h0h[swz512(row, c)] =
              rne_bf16(fmaxf(fmaf(acc[mi][reg], s, sh), 0.f));
        }
    }
    __syncthreads();
    // L1 (32x32): h1 = relu(bn(h0 @ eW1[e] + eb1));
    // wave w -> n-tile (w>>1), m-tiles {(w&1)*2, (w&1)*2+1}
    {
      const int nt1 = w >> 1, mb = (w & 1) * 2;
      f32x16 acc[2] = {};
      #pragma unroll
      for (int kt = 0; kt < 16; ++kt) {
        const size_t tp = TPO_EW1 + (size_t)e * 64 + (size_t)nt1 * 16 + kt;
        const bf16x8 wh = *((const bf16x8*)(ws + tp * 1024) + l);
        bf16x8 ah[2];
        #pragma unroll
        for (int mi = 0; mi < 2; ++mi)
          ah[mi] = ldA(sm.h0h, swz512((mb + mi) * 32 + rB, kt * 16 + kg8b));
        #pragma unroll
        for (int mi = 0; mi < 2; ++mi)
          acc[mi] = MFMA32(ah[mi], wh, acc[mi]);
      }
      const int c = nt1 * 32 + rB;
      const float s  = e1g[e * H1 + c] * rsqrtf(e1v[e * H1 + c] + EPS);
      const float sh = fmaf(eb1[e * H1 + c] - e1m[e * H1 + c], s, e1b[e * H1 + c]);
      #pragma unroll
      for (int mi = 0; mi < 2; ++mi)
        #pragma unroll
        for (int reg = 0; reg < 16; ++reg) {
          const int row = (mb + mi) * 32 + (reg & 3) + 8 * (reg >> 2) + hb4;
          sm.u.h1h[swz256(row, c)] =
              rne_bf16(fmaxf(fmaf(acc[mi][reg], s, sh), 0.f));
        }
    }
    __syncthreads();
    // L2 + gated combine (16x16, h2 stays in registers);
    // wave -> m-tiles {2wg, 2wg+1}, n-tiles {2np, 2np+1}
    #pragma unroll
    for (int nti = 0; nti < 2; ++nti) {
      f32x4 acc2[2] = {};
      #pragma unroll
      for (int kt = 0; kt < 4; ++kt) {
        const size_t tp = TPO_EW2 + ((size_t)e * 4 + 2 * np + nti) * 4 + kt;
        const bf16x8 wh = *((const bf16x8*)(ws + tp * 1024) + l);
        #pragma unroll
        for (int mi = 0; mi < 2; ++mi) {
          const bf16x8 ah = ldA(sm.u.h1h, swz256((2 * wg + mi) * 16 + rA, kt * 32 + kg8));
          acc2[mi] = MFMA16(ah, wh, acc2[mi]);
        }
      }
      const int c = (2 * np + nti) * 16 + rA;
      const float s  = e2g[e * H2 + c] * rsqrtf(e2v[e * H2 + c] + EPS);
      const float sh = fmaf(eb2[e * H2 + c] - e2m[e * H2 + c], s, e2b[e * H2 + c]);
      #pragma unroll
      for (int mi = 0; mi < 2; ++mi)
        #pragma unroll
        for (int r = 0; r < 4; ++r) {
          const float gt = __shfl(gmine[mi][r], (l & 48) | e);  // gate[row][e]
          comb[mi][nti][r] = fmaf(gt, fmaxf(fmaf(acc2[mi][r], s, sh), 0.f),
                                  comb[mi][nti][r]);
        }
    }
    // hazard-free: h0h rewritten only after post-L1 barrier of this expert;
    // h1h rewritten only after post-L0 barrier of next expert.
  }

  // ---- Phase F: out = comb @ oW + ob (part aliases h1h -> barrier first)
  const float w0 = oW[(2 * np + 0) * 16 + rA];
  const float w1 = oW[(2 * np + 1) * 16 + rA];
  __syncthreads();
  #pragma unroll
  for (int mi = 0; mi < 2; ++mi)
    #pragma unroll
    for (int r = 0; r < 4; ++r) {
      float sx = comb[mi][0][r] * w0 + comb[mi][1][r] * w1;
      sx += __shfl_xor(sx, 1);
      sx += __shfl_xor(sx, 2);
      sx += __shfl_xor(sx, 4);
      sx += __shfl_xor(sx, 8);
      if (rA == 0) sm.u.part[wg][np][mi * 16 + lg4 + r] = sx;
    }
  __syncthreads();
  if (t < TBR)
    out[row0 + t] = sm.u.part[t >> 5][0][t & 31] +
                    sm.u.part[t >> 5][1][t & 31] + ob[0];
}

// ------------------------------------------------- fp32 fallback (verified) -
struct SmemF {
  float xn[16][D]; float h0[16][H0]; float h1[16][H1]; float gates[16][NE];
};
__global__ __launch_bounds__(256, 2) void moe_fused_fp32(
    const float* __restrict__ x,
    const float* __restrict__ in_g, const float* __restrict__ in_b,
    const float* __restrict__ in_m, const float* __restrict__ in_v,
    const float* __restrict__ gW1, const float* __restrict__ gb1,
    const float* __restrict__ g_g, const float* __restrict__ g_b,
    const float* __restrict__ g_m, const float* __restrict__ g_v,
    const float* __restrict__ gW2, const float* __restrict__ gb2,
    const float* __restrict__ eW0, const float* __restrict__ eb0,
    const float* __restrict__ e0g, const float* __restrict__ e0b,
    const float* __restrict__ e0m, const float* __restrict__ e0v,
    const float* __restrict__ eW1, const float* __restrict__ eb1,
    const float* __restrict__ e1g, const float* __restrict__ e1b,
    const float* __restrict__ e1m, const float* __restrict__ e1v,
    const float* __restrict__ eW2, const float* __restrict__ eb2,
    const float* __restrict__ e2g, const float* __restrict__ e2b,
    const float* __restrict__ e2m, const float* __restrict__ e2v,
    const float* __restrict__ oW, const float* __restrict__ ob,
    float* __restrict__ out)
{
  __shared__ SmemF sm;
  const int t = threadIdx.x;
  const int row0 = blockIdx.x * 16;
  {
    const int c = t;
    const float s  = in_g[c] * rsqrtf(in_v[c] + EPS);
    const float sh = in_b[c] - in_m[c] * s;
    #pragma unroll
    for (int r = 0; r < 16; ++r)
      sm.xn[r][c] = fmaf(x[(size_t)(row0 + r) * D + c], s, sh);
  }
  __syncthreads();
  {
    const int rg = t >> 6, c0 = (t & 63) * 2;
    float acc[4][2] = {};
    for (int k = 0; k < D; k += 4) {
      float4 xa[4];
      #pragma unroll
      for (int r = 0; r < 4; ++r) xa[r] = *(const float4*)(&sm.xn[rg * 4 + r][k]);
      float2 wv[4];
      #pragma unroll
      for (int kk = 0; kk < 4; ++kk) wv[kk] = *(const float2*)(&gW1[(size_t)(k + kk) * G + c0]);
      #pragma unroll
      for (int r = 0; r < 4; ++r) {
        const float* xv = (const float*)&xa[r];
        #pragma unroll
        for (int kk = 0; kk < 4; ++kk) {
          acc[r][0] = fmaf(xv[kk], wv[kk].x, acc[r][0]);
          acc[r][1] = fmaf(xv[kk], wv[kk].y, acc[r][1]);
        }
      }
    }
    #pragma unroll
    for (int j = 0; j < 2; ++j) {
      const int c = c0 + j;
      const float s  = g_g[c] * rsqrtf(g_v[c] + EPS);
      const float sh = fmaf(gb1[c] - g_m[c], s, g_b[c]);
      #pragma unroll
      for (int r = 0; r < 4; ++r)
        sm.h1[rg * 4 + r][c] = fmaxf(fmaf(acc[r][j], s, sh), 0.f);
    }
  }
  __syncthreads();
  if (t < 16 * NE) {
    const int r = t >> 3, e = t & 7;
    float acc = gb2[e];
    for (int k = 0; k < G; k += 4) {
      const float4 hv = *(const float4*)(&sm.h1[r][k]);
      acc = fmaf(hv.x, gW2[(k + 0) * NE + e], acc);
      acc = fmaf(hv.y, gW2[(k + 1) * NE + e], acc);
      acc = fmaf(hv.z, gW2[(k + 2) * NE + e], acc);
      acc = fmaf(hv.w, gW2[(k + 3) * NE + e], acc);
    }
    sm.gates[r][e] = acc;
  }
  __syncthreads();
  if (t < 16) {
    float v[NE]; float mx = -3.4e38f;
    #pragma unroll
    for (int e = 0; e < NE; ++e) { v[e] = sm.gates[t][e]; mx = fmaxf(mx, v[e]); }
    float ssum = 0.f;
    #pragma unroll
    for (int e = 0; e < NE; ++e) { v[e] = expf(v[e] - mx); ssum += v[e]; }
    const float inv = 1.f / ssum;
    #pragma unroll
    for (int e = 0; e < NE; ++e) sm.gates[t][e] = v[e] * inv;
  }
  __syncthreads();
  float comb[4] = {0.f, 0.f, 0.f, 0.f};
  const int rgA = t >> 6, c0A = (t & 63) * 4;
  const int rg1 = t >> 5, c01 = (t & 31) * 4;
  const int r2  = t >> 4, c02 = (t & 15) * 4;
  for (int e = 0; e < NE; ++e) {
    {
      const float* __restrict__ W = eW0 + (size_t)e * D * H0;
      float acc[4][4] = {};
      for (int k = 0; k < D; k += 4) {
        float4 xa[4];
        #pragma unroll
        for (int r = 0; r < 4; ++r) xa[r] = *(const float4*)(&sm.xn[rgA * 4 + r][k]);
        float4 wv[4];
        #pragma unroll
        for (int kk = 0; kk < 4; ++kk) wv[kk] = *(const float4*)(&W[(size_t)(k + kk) * H0 + c0A]);
        #pragma unroll
        for (int r = 0; r < 4; ++r) {
          const float* xv = (const float*)&xa[r];
          #pragma unroll
          for (int kk = 0; kk < 4; ++kk) {
            acc[r][0] = fmaf(xv[kk], wv[kk].x, acc[r][0]);
            acc[r][1] = fmaf(xv[kk], wv[kk].y, acc[r][1]);
            acc[r][2] = fmaf(xv[kk], wv[kk].z, acc[r][2]);
            acc[r][3] = fmaf(xv[kk], wv[kk].w, acc[r][3]);
          }
        }
      }
      const float4 gg = *(const float4*)(&e0g[e * H0 + c0A]);
      const float4 bb = *(const float4*)(&e0b[e * H0 + c0A]);
      const float4 mm = *(const float4*)(&e0m[e * H0 + c0A]);
      const float4 vv = *(const float4*)(&e0v[e * H0 + c0A]);
      const float4 bi = *(const float4*)(&eb0[e * H0 + c0A]);
      float s[4], sh[4];
      s[0] = gg.x * rsqrtf(vv.x + EPS); sh[0] = fmaf(bi.x - mm.x, s[0], bb.x);
      s[1] = gg.y * rsqrtf(vv.y + EPS); sh[1] = fmaf(bi.y - mm.y, s[1], bb.y);
      s[2] = gg.z * rsqrtf(vv.z + EPS); sh[2] = fmaf(bi.z - mm.z, s[2], bb.z);
      s[3] = gg.w * rsqrtf(vv.w + EPS); sh[3] = fmaf(bi.w - mm.w, s[3], bb.w);
      #pragma unroll
      for (int r = 0; r < 4; ++r) {
        float4 o;
        o.x = fmaxf(fmaf(acc[r][0], s[0], sh[0]), 0.f);
        o.y = fmaxf(fmaf(acc[r][1], s[1], sh[1]), 0.f);
        o.z = fmaxf(fmaf(acc[r][2], s[2], sh[2]), 0.f);
        o.w = fmaxf(fmaf(acc[r][3], s[3], sh[3]), 0.f);
        *(float4*)(&sm.h0[rgA * 4 + r][c0A]) = o;
      }
    }
    __syncthreads();
    {
      const float* __restrict__ W = eW1 + (size_t)e * H0 * H1;
      float acc[2][4] = {};
      for (int k = 0; k < H0; k += 4) {
        float4 xa[2];
        #pragma unroll
        for (int r = 0; r < 2; ++r) xa[r] = *(const float4*)(&sm.h0[rg1 * 2 + r][k]);
        float4 wv[4];
        #pragma unroll
        for (int kk = 0; kk < 4; ++kk) wv[kk] = *(const float4*)(&W[(size_t)(k + kk) * H1 + c01]);
        #pragma unroll
        for (int r = 0; r < 2; ++r) {
          const float* xv = (const float*)&xa[r];
          #pragma unroll
          for (int kk = 0; kk < 4; ++kk) {
            acc[r][0] = fmaf(xv[kk], wv[kk].x, acc[r][0]);
            acc[r][1] = fmaf(xv[kk], wv[kk].y, acc[r][1]);
            acc[r][2] = fmaf(xv[kk], wv[kk].z, acc[r][2]);
            acc[r][3] = fmaf(xv[kk], wv[kk].w, acc[r][3]);
          }
        }
      }
      const float4 gg = *(const float4*)(&e1g[e * H1 + c01]);
      const float4 bb = *(const float4*)(&e1b[e * H1 + c01]);
      const float4 mm = *(const float4*)(&e1m[e * H1 + c01]);
      const float4 vv = *(const float4*)(&e1v[e * H1 + c01]);
      const float4 bi = *(const float4*)(&eb1[e * H1 + c01]);
      float s[4], sh[4];
      s[0] = gg.x * rsqrtf(vv.x + EPS); sh[0] = fmaf(bi.x - mm.x, s[0], bb.x);
      s[1] = gg.y * rsqrtf(vv.y + EPS); sh[1] = fmaf(bi.y - mm.y, s[1], bb.y);
      s[2] = gg.z * rsqrtf(vv.z + EPS); sh[2] = fmaf(bi.z - mm.z, s[2], bb.z);
      s[3] = gg.w * rsqrtf(vv.w + EPS); sh[3] = fmaf(bi.w - mm.w, s[3], bb.w);
      #pragma unroll
      for (int r = 0; r < 2; ++r) {
        float4 o;
        o.x = fmaxf(fmaf(acc[r][0], s[0], sh[0]), 0.f);
        o.y = fmaxf(fmaf(acc[r][1], s[1], sh[1]), 0.f);
        o.z = fmaxf(fmaf(acc[r][2], s[2], sh[2]), 0.f);
        o.w = fmaxf(fmaf(acc[r][3], s[3], sh[3]), 0.f);
        *(float4*)(&sm.h1[rg1 * 2 + r][c01]) = o;
      }
    }
    __syncthreads();
    {
      const float* __restrict__ W = eW2 + (size_t)e * H1 * H2;
      float acc[4] = {};
      for (int k = 0; k < H1; k += 4) {
        const float4 xa = *(const float4*)(&sm.h1[r2][k]);
        const float4 w0 = *(const float4*)(&W[(size_t)(k + 0) * H2 + c02]);
        const float4 w1 = *(const float4*)(&W[(size_t)(k + 1) * H2 + c02]);
        const float4 w2 = *(const float4*)(&W[(size_t)(k + 2) * H2 + c02]);
        const float4 w3 = *(const float4*)(&W[(size_t)(k + 3) * H2 + c02]);
        acc[0] = fmaf(xa.x, w0.x, acc[0]); acc[1] = fmaf(xa.x, w0.y, acc[1]);
        acc[2] = fmaf(xa.x, w0.z, acc[2]); acc[3] = fmaf(xa.x, w0.w, acc[3]);
        acc[0] = fmaf(xa.y, w1.x, acc[0]); acc[1] = fmaf(xa.y, w1.y, acc[1]);
        acc[2] = fmaf(xa.y, w1.z, acc[2]); acc[3] = fmaf(xa.y, w1.w, acc[3]);
        acc[0] = fmaf(xa.z, w2.x, acc[0]); acc[1] = fmaf(xa.z, w2.y, acc[1]);
        acc[2] = fmaf(xa.z, w2.z, acc[2]); acc[3] = fmaf(xa.z, w2.w, acc[3]);
        acc[0] = fmaf(xa.w, w3.x, acc[0]); acc[1] = fmaf(xa.w, w3.y, acc[1]);
        acc[2] = fmaf(xa.w, w3.z, acc[2]); acc[3] = fmaf(xa.w, w3.w, acc[3]);
      }
      const float4 gg = *(const float4*)(&e2g[e * H2 + c02]);
      const float4 bb = *(const float4*)(&e2b[e * H2 + c02]);
      const float4 mm = *(const float4*)(&e2m[e * H2 + c02]);
      const float4 vv = *(const float4*)(&e2v[e * H2 + c02]);
      const float4 bi = *(const float4*)(&eb2[e * H2 + c02]);
      float s[4], sh[4];
      s[0] = gg.x * rsqrtf(vv.x + EPS); sh[0] = fmaf(bi.x - mm.x, s[0], bb.x);
      s[1] = gg.y * rsqrtf(vv.y + EPS); sh[1] = fmaf(bi.y - mm.y, s[1], bb.y);
      s[2] = gg.z * rsqrtf(vv.z + EPS); sh[2] = fmaf(bi.z - mm.z, s[2], bb.z);
      s[3] = gg.w * rsqrtf(vv.w + EPS); sh[3] = fmaf(bi.w - mm.w, s[3], bb.w);
      const float gate = sm.gates[r2][e];
      comb[0] = fmaf(gate, fmaxf(fmaf(acc[0], s[0], sh[0]), 0.f), comb[0]);
      comb[1] = fmaf(gate, fmaxf(fmaf(acc[1], s[1], sh[1]), 0.f), comb[1]);
      comb[2] = fmaf(gate, fmaxf(fmaf(acc[2], s[2], sh[2]), 0.f), comb[2]);
      comb[3] = fmaf(gate, fmaxf(fmaf(acc[3], s[3], sh[3]), 0.f), comb[3]);
    }
  }
  float part = comb[0] * oW[c02 + 0] + comb[1] * oW[c02 + 1] +
               comb[2] * oW[c02 + 2] + comb[3] * oW[c02 + 3];
  part += __shfl_xor(part, 1);
  part += __shfl_xor(part, 2);
  part += __shfl_xor(part, 4);
  part += __shfl_xor(part, 8);
  if ((t & 15) == 0) out[row0 + r2] = part + ob[0];
}

// ------------------------------------------------------------------ launch --
extern "C" void kernel_launch(void* const* d_in, const int* in_sizes, int n_in,
                              void* d_out, int out_size, void* d_ws, size_t ws_size,
                              hipStream_t stream) {
  const float* x    = (const float*)d_in[0];
  const float* in_g = (const float*)d_in[1];
  const float* in_b = (const float*)d_in[2];
  const float* in_m = (const float*)d_in[3];
  const float* in_v = (const float*)d_in[4];
  const float* gW1  = (const float*)d_in[5];
  const float* gb1  = (const float*)d_in[6];
  const float* g_g  = (const float*)d_in[7];
  const float* g_b  = (const float*)d_in[8];
  const float* g_m  = (const float*)d_in[9];
  const float* g_v  = (const float*)d_in[10];
  const float* gW2  = (const float*)d_in[11];
  const float* gb2  = (const float*)d_in[12];
  const float* eW0  = (const float*)d_in[13];
  const float* eb0  = (const float*)d_in[14];
  const float* e0g  = (const float*)d_in[15];
  const float* e0b  = (const float*)d_in[16];
  const float* e0m  = (const float*)d_in[17];
  const float* e0v  = (const float*)d_in[18];
  const float* eW1  = (const float*)d_in[19];
  const float* eb1  = (const float*)d_in[20];
  const float* e1g  = (const float*)d_in[21];
  const float* e1b  = (const float*)d_in[22];
  const float* e1m  = (const float*)d_in[23];
  const float* e1v  = (const float*)d_in[24];
  const float* eW2  = (const float*)d_in[25];
  const float* eb2  = (const float*)d_in[26];
  const float* e2g  = (const float*)d_in[27];
  const float* e2b  = (const float*)d_in[28];
  const float* e2m  = (const float*)d_in[29];
  const float* e2v  = (const float*)d_in[30];
  const float* oW   = (const float*)d_in[31];
  const float* ob   = (const float*)d_in[32];
  float* out = (float*)d_out;
  const int Btot = in_sizes[0] / D;

  if (ws_size >= WS_BYTES && (Btot % TBR) == 0) {
    u16* ws = (u16*)d_ws;
    repack_w<<<TP_TOTAL / 4, 256, 0, stream>>>(eW0, eW1, eW2, gW1, gW2, ws);
    moe_mfma<<<Btot / TBR, NT, 0, stream>>>(
        x, in_g, in_b, in_m, in_v,
        gb1, g_g, g_b, g_m, g_v, gb2,
        eb0, e0g, e0b, e0m, e0v,
        eb1, e1g, e1b, e1m, e1v,
        eb2, e2g, e2b, e2m, e2v,
        oW, ob, ws, out);
  } else {
    moe_fused_fp32<<<Btot / 16, 256, 0, stream>>>(
        x, in_g, in_b, in_m, in_v,
        gW1, gb1, g_g, g_b, g_m, g_v, gW2, gb2,
        eW0, eb0, e0g, e0b, e0m, e0v,
        eW1, eb1, e1g, e1b, e1m, e1v,
        eW2, eb2, e2g, e2b, e2m, e2v,
        oW, ob, out);
  }
}